// Round 1
// baseline (11701.966 us; speedup 1.0000x reference)
//
#include <hip/hip_runtime.h>
#include <hip/hip_bf16.h>
#include <math.h>

// Problem constants
#define LAYERS 4
#define NHEAD  12
#define DMODEL 768
#define HEADD  64
#define NCTX   2048
#define NVOCAB 50257
#define D3     (3*DMODEL)
#define D4     (4*DMODEL)

// ---------------------------------------------------------------------------
// Embedding: x[c,d] = vocab_embed[tok[c]][d] + pos_embed[c][d]
// ---------------------------------------------------------------------------
__global__ void embed_k(const int* __restrict__ tok,
                        const float* __restrict__ ve,
                        const float* __restrict__ pe,
                        float* __restrict__ x) {
    int c = blockIdx.x;
    int t = tok[c];
    for (int d = threadIdx.x; d < DMODEL; d += blockDim.x)
        x[(size_t)c * DMODEL + d] = ve[(size_t)t * DMODEL + d] + pe[(size_t)c * DMODEL + d];
}

// ---------------------------------------------------------------------------
// LayerNorm, one block per row. y = (x-mu)*rsqrt(var+eps)*g + b
// ---------------------------------------------------------------------------
__global__ void layernorm_k(const float* __restrict__ x,
                            const float* __restrict__ g,
                            const float* __restrict__ b,
                            float* __restrict__ y) {
    const int row = blockIdx.x;
    const float* xr = x + (size_t)row * DMODEL;
    __shared__ float red[256];
    const int tid = threadIdx.x;

    float s = 0.f;
    for (int d = tid; d < DMODEL; d += 256) s += xr[d];
    red[tid] = s; __syncthreads();
    for (int off = 128; off > 0; off >>= 1) {
        if (tid < off) red[tid] += red[tid + off];
        __syncthreads();
    }
    const float mu = red[0] / DMODEL;
    __syncthreads();

    float v = 0.f;
    for (int d = tid; d < DMODEL; d += 256) { float t = xr[d] - mu; v += t * t; }
    red[tid] = v; __syncthreads();
    for (int off = 128; off > 0; off >>= 1) {
        if (tid < off) red[tid] += red[tid + off];
        __syncthreads();
    }
    const float rstd = rsqrtf(red[0] / DMODEL + 1e-5f);

    for (int d = tid; d < DMODEL; d += 256)
        y[(size_t)row * DMODEL + d] = (xr[d] - mu) * rstd * g[d] + b[d];
}

// ---------------------------------------------------------------------------
// Generic f32 GEMM: C[M,N] = act(A[M,K] @ B[K,N] + bias[N]) + addsrc[M,N]
// act: 0 = none, 1 = tanh-GELU. 64x64 tile, BK=16, 256 threads, 4x4/thread.
// ---------------------------------------------------------------------------
#define BM 64
#define BN 64
#define BK 16
__global__ __launch_bounds__(256)
void gemm_f32(const float* __restrict__ A, const float* __restrict__ B,
              const float* __restrict__ bias, const float* __restrict__ addsrc,
              float* __restrict__ C, int M, int N, int K, int act) {
    __shared__ float As[BK][BM];
    __shared__ float Bs[BK][BN];

    const int bm = blockIdx.y * BM;
    const int bn = blockIdx.x * BN;
    const int tid = threadIdx.x;
    const int tr = tid >> 4;    // 0..15
    const int tc = tid & 15;    // 0..15

    float acc[4][4] = {};

    for (int k0 = 0; k0 < K; k0 += BK) {
        // A tile: 64 rows x 16 k  (1024 elems, 4 per thread)
        #pragma unroll
        for (int i = 0; i < 4; i++) {
            int idx = tid + i * 256;
            int row = idx >> 4;         // m in tile
            int col = idx & 15;         // k in tile
            int gm = bm + row;
            float v = 0.f;
            if (gm < M) v = A[(size_t)gm * K + (k0 + col)];
            As[col][row] = v;
        }
        // B tile: 16 k x 64 n
        #pragma unroll
        for (int i = 0; i < 4; i++) {
            int idx = tid + i * 256;
            int row = idx >> 6;         // k in tile
            int col = idx & 63;         // n in tile
            int gn = bn + col;
            float v = 0.f;
            if (gn < N) v = B[(size_t)(k0 + row) * N + gn];
            Bs[row][col] = v;
        }
        __syncthreads();

        #pragma unroll
        for (int kk = 0; kk < BK; kk++) {
            float a[4], bb[4];
            #pragma unroll
            for (int i = 0; i < 4; i++) a[i] = As[kk][tr * 4 + i];
            #pragma unroll
            for (int j = 0; j < 4; j++) bb[j] = Bs[kk][tc * 4 + j];
            #pragma unroll
            for (int i = 0; i < 4; i++)
                #pragma unroll
                for (int j = 0; j < 4; j++)
                    acc[i][j] += a[i] * bb[j];
        }
        __syncthreads();
    }

    #pragma unroll
    for (int i = 0; i < 4; i++) {
        int gm = bm + tr * 4 + i;
        if (gm >= M) continue;
        #pragma unroll
        for (int j = 0; j < 4; j++) {
            int gn = bn + tc * 4 + j;
            if (gn >= N) continue;
            float v = acc[i][j] + (bias ? bias[gn] : 0.f);
            if (act == 1) {
                const float cst = 0.7978845608028654f; // sqrt(2/pi)
                float t = tanhf(cst * (v + 0.044715f * v * v * v));
                v = 0.5f * v * (1.f + t);
            }
            if (addsrc) v += addsrc[(size_t)gm * N + gn];
            C[(size_t)gm * N + gn] = v;
        }
    }
}

// ---------------------------------------------------------------------------
// Causal attention for one (query row, head) per block. 256 threads.
// qkv layout: [C, 3*D]; q at h*64, k at D + h*64, v at 2D + h*64.
// o layout: [C, D].
// ---------------------------------------------------------------------------
__global__ __launch_bounds__(256)
void attn_k(const float* __restrict__ qkv, float* __restrict__ o) {
    const int q = blockIdx.x;
    const int h = blockIdx.y;
    const int tid = threadIdx.x;

    __shared__ float qrow[HEADD];
    __shared__ float sc[NCTX];
    __shared__ float red[256];
    __shared__ float part[4][HEADD];

    if (tid < HEADD) qrow[tid] = qkv[(size_t)q * D3 + h * HEADD + tid];
    __syncthreads();

    const float scale = 0.125f; // 1/sqrt(64)

    // scores for k = 0..q
    float lmax = -1e30f;
    for (int k = tid; k <= q; k += 256) {
        const float* kr = qkv + (size_t)k * D3 + DMODEL + h * HEADD;
        float s = 0.f;
        #pragma unroll
        for (int d = 0; d < HEADD; d++) s += qrow[d] * kr[d];
        s *= scale;
        sc[k] = s;
        lmax = fmaxf(lmax, s);
    }
    red[tid] = lmax; __syncthreads();
    for (int off = 128; off > 0; off >>= 1) {
        if (tid < off) red[tid] = fmaxf(red[tid], red[tid + off]);
        __syncthreads();
    }
    const float m = red[0];
    __syncthreads();

    float lsum = 0.f;
    for (int k = tid; k <= q; k += 256) {
        float p = expf(sc[k] - m);
        sc[k] = p;
        lsum += p;
    }
    red[tid] = lsum; __syncthreads();
    for (int off = 128; off > 0; off >>= 1) {
        if (tid < off) red[tid] += red[tid + off];
        __syncthreads();
    }
    const float inv = 1.f / red[0];

    // PV: 4 groups of 64 lanes, group g takes k = g, g+4, ...
    const int grp = tid >> 6;
    const int d = tid & 63;
    float acc = 0.f;
    for (int k = grp; k <= q; k += 4)
        acc += sc[k] * qkv[(size_t)k * D3 + 2 * DMODEL + h * HEADD + d];
    part[grp][d] = acc;
    __syncthreads();

    if (tid < HEADD) {
        float v = (part[0][tid] + part[1][tid] + part[2][tid] + part[3][tid]) * inv;
        o[(size_t)q * DMODEL + h * HEADD + tid] = v;
    }
}

// ---------------------------------------------------------------------------
// Launch
// ---------------------------------------------------------------------------
extern "C" void kernel_launch(void* const* d_in, const int* in_sizes, int n_in,
                              void* d_out, int out_size, void* d_ws, size_t ws_size,
                              hipStream_t stream) {
    const int*   tokens      = (const int*)  d_in[0];
    const float* vocab_embed = (const float*)d_in[1];
    const float* pos_embed   = (const float*)d_in[2];
    const float* ln1_g       = (const float*)d_in[3];
    const float* ln1_b       = (const float*)d_in[4];
    const float* att_w       = (const float*)d_in[5];
    const float* att_b       = (const float*)d_in[6];
    const float* attn_proj_w = (const float*)d_in[7];
    const float* attn_proj_b = (const float*)d_in[8];
    const float* ln2_g       = (const float*)d_in[9];
    const float* ln2_b       = (const float*)d_in[10];
    const float* fc_w        = (const float*)d_in[11];
    const float* fc_b        = (const float*)d_in[12];
    const float* mlp_proj_w  = (const float*)d_in[13];
    const float* mlp_proj_b  = (const float*)d_in[14];
    const float* lnf_g       = (const float*)d_in[15];
    const float* lnf_b       = (const float*)d_in[16];
    const float* out_w       = (const float*)d_in[17];
    const float* out_b       = (const float*)d_in[18];
    float* out = (float*)d_out;

    const int C = NCTX;

    // Scratch layout (floats): x[C*D], h[C*D], o[C*D], qkv[C*3D], mid[C*4D]
    const size_t n_x   = (size_t)C * DMODEL;
    const size_t n_qkv = (size_t)C * D3;
    const size_t n_mid = (size_t)C * D4;
    const size_t need_bytes = (3 * n_x + n_qkv + n_mid) * sizeof(float);

    float *x, *h, *o, *qkv, *mid;
    float* ws = (float*)d_ws;
    if (ws_size >= need_bytes) {
        x   = ws;
        h   = x + n_x;
        o   = h + n_x;
        qkv = o + n_x;
        mid = qkv + n_qkv;
    } else {
        // fall back: park big temporaries at the front of d_out (it is only
        // produced by the very last GEMM, after qkv/mid are dead)
        x   = ws;
        h   = x + n_x;
        o   = h + n_x;
        qkv = (float*)d_out;
        mid = qkv + n_qkv;
    }

    dim3 blk(256);

    // embedding
    embed_k<<<dim3(C), blk, 0, stream>>>(tokens, vocab_embed, pos_embed, x);

    for (int l = 0; l < LAYERS; l++) {
        const float* lw;

        // h = LN1(x)
        layernorm_k<<<dim3(C), blk, 0, stream>>>(x, ln1_g + l * DMODEL, ln1_b + l * DMODEL, h);

        // qkv = h @ att_w[l] + att_b[l]
        lw = att_w + (size_t)l * DMODEL * D3;
        gemm_f32<<<dim3(D3 / BN, C / BM), blk, 0, stream>>>(
            h, lw, att_b + l * D3, nullptr, qkv, C, D3, DMODEL, 0);

        // o = attention(qkv)
        attn_k<<<dim3(C, NHEAD), blk, 0, stream>>>(qkv, o);

        // x = h + o @ attn_proj_w[l] + attn_proj_b[l]
        lw = attn_proj_w + (size_t)l * DMODEL * DMODEL;
        gemm_f32<<<dim3(DMODEL / BN, C / BM), blk, 0, stream>>>(
            o, lw, attn_proj_b + l * DMODEL, h, x, C, DMODEL, DMODEL, 0);

        // h = LN2(x)   (h2)
        layernorm_k<<<dim3(C), blk, 0, stream>>>(x, ln2_g + l * DMODEL, ln2_b + l * DMODEL, h);

        // mid = gelu(h @ fc_w[l] + fc_b[l])
        lw = fc_w + (size_t)l * DMODEL * D4;
        gemm_f32<<<dim3(D4 / BN, C / BM), blk, 0, stream>>>(
            h, lw, fc_b + l * D4, nullptr, mid, C, D4, DMODEL, 1);

        // x = h + mid @ mlp_proj_w[l] + mlp_proj_b[l]
        lw = mlp_proj_w + (size_t)l * D4 * DMODEL;
        gemm_f32<<<dim3(DMODEL / BN, C / BM), blk, 0, stream>>>(
            mid, lw, mlp_proj_b + l * DMODEL, h, x, C, DMODEL, D4, 0);
    }

    // h = LN_f(x)
    layernorm_k<<<dim3(C), blk, 0, stream>>>(x, lnf_g, lnf_b, h);

    // logits = h @ out_w + out_b
    gemm_f32<<<dim3((NVOCAB + BN - 1) / BN, C / BM), blk, 0, stream>>>(
        h, out_w, out_b, nullptr, out, C, NVOCAB, DMODEL, 0);
}

// Round 2
// 5014.032 us; speedup vs baseline: 2.3338x; 2.3338x over previous
//
#include <hip/hip_runtime.h>
#include <hip/hip_bf16.h>
#include <math.h>

// Problem constants
#define LAYERS 4
#define NHEAD  12
#define DMODEL 768
#define HEADD  64
#define NCTX   2048
#define NVOCAB 50257
#define NVPAD  50304            // 393*128
#define D3     (3*DMODEL)
#define D4     (4*DMODEL)

typedef short short8 __attribute__((ext_vector_type(8)));
typedef float f32x4  __attribute__((ext_vector_type(4)));

__device__ __forceinline__ float bf2f(ushort u) {
    union { uint i; float f; } c; c.i = ((uint)u) << 16; return c.f;
}
__device__ __forceinline__ ushort f2bf(float f) {
    union { float f; uint i; } c; c.f = f;
    uint i = c.i;
    uint r = (i + 0x7FFFu + ((i >> 16) & 1u)) >> 16;   // round-nearest-even
    return (ushort)r;
}

#define GLD16(gp, lp) __builtin_amdgcn_global_load_lds( \
    (__attribute__((address_space(1))) void*)(gp),      \
    (__attribute__((address_space(3))) void*)(lp), 16, 0, 0)

// ---------------------------------------------------------------------------
// Embedding: x[c,d] = vocab_embed[tok[c]][d] + pos_embed[c][d]  (f32)
// ---------------------------------------------------------------------------
__global__ void embed_k(const int* __restrict__ tok,
                        const float* __restrict__ ve,
                        const float* __restrict__ pe,
                        float* __restrict__ x) {
    int c = blockIdx.x;
    int t = tok[c];
    for (int d = threadIdx.x; d < DMODEL; d += blockDim.x)
        x[(size_t)c * DMODEL + d] = ve[(size_t)t * DMODEL + d] + pe[(size_t)c * DMODEL + d];
}

// ---------------------------------------------------------------------------
// LayerNorm, one block per row. Writes f32 (optional) and bf16 (optional).
// ---------------------------------------------------------------------------
__global__ void layernorm_k(const float* __restrict__ x,
                            const float* __restrict__ g,
                            const float* __restrict__ b,
                            float* __restrict__ yf,
                            ushort* __restrict__ ybf) {
    const int row = blockIdx.x;
    const float* xr = x + (size_t)row * DMODEL;
    __shared__ float red[256];
    const int tid = threadIdx.x;

    float s = 0.f;
    for (int d = tid; d < DMODEL; d += 256) s += xr[d];
    red[tid] = s; __syncthreads();
    for (int off = 128; off > 0; off >>= 1) {
        if (tid < off) red[tid] += red[tid + off];
        __syncthreads();
    }
    const float mu = red[0] / DMODEL;
    __syncthreads();

    float v = 0.f;
    for (int d = tid; d < DMODEL; d += 256) { float t = xr[d] - mu; v += t * t; }
    red[tid] = v; __syncthreads();
    for (int off = 128; off > 0; off >>= 1) {
        if (tid < off) red[tid] += red[tid + off];
        __syncthreads();
    }
    const float rstd = rsqrtf(red[0] / DMODEL + 1e-5f);

    for (int d = tid; d < DMODEL; d += 256) {
        float r = (xr[d] - mu) * rstd * g[d] + b[d];
        if (yf)  yf[(size_t)row * DMODEL + d] = r;
        if (ybf) ybf[(size_t)row * DMODEL + d] = f2bf(r);
    }
}

// ---------------------------------------------------------------------------
// Transpose + f32->bf16 convert: src [K,N] row-major f32 -> dst [Npad,K] bf16.
// K, Npad multiples of 32. n >= N produces 0 rows.
// ---------------------------------------------------------------------------
__global__ __launch_bounds__(256) void transp_bf16(const float* __restrict__ src,
                                                   ushort* __restrict__ dst,
                                                   int K, int N) {
    __shared__ float tile[32][33];
    const int nt = blockIdx.x * 32, kt = blockIdx.y * 32;
    const int t = threadIdx.x;
    const int lr = t >> 5, lc = t & 31;   // 8 rows x 32 cols per pass

    #pragma unroll
    for (int i = 0; i < 4; i++) {
        int k = kt + lr + i * 8, n = nt + lc;
        float v = (n < N) ? src[(size_t)k * N + n] : 0.f;
        tile[lr + i * 8][lc] = v;
    }
    __syncthreads();
    #pragma unroll
    for (int i = 0; i < 4; i++) {
        int n = nt + lr + i * 8, k = kt + lc;
        dst[(size_t)n * K + k] = f2bf(tile[lc][lr + i * 8]);
    }
}

// ---------------------------------------------------------------------------
// bf16 MFMA GEMM. A [M,K] bf16 row-major, Bt [Npad,K] bf16 (B transposed).
// C = act(A@B + bias) (+ addsrc).  128x128 tile, BK=32, 256 thr, 4 waves.
// ACT: 0 none, 1 tanh-GELU. OUTBF: write bf16 (else f32).
// ---------------------------------------------------------------------------
template<int ACT, bool HASADD, bool OUTBF>
__global__ __launch_bounds__(256) void gemm_bf16(
    const ushort* __restrict__ A, const ushort* __restrict__ Bt,
    const float* __restrict__ bias, const float* __restrict__ addsrc,
    void* __restrict__ Cout, int N, int K)
{
    __shared__ __align__(16) ushort As[128 * 32];
    __shared__ __align__(16) ushort Bs[128 * 32];
    const int bm = blockIdx.y * 128, bn = blockIdx.x * 128;
    const int t = threadIdx.x, l = t & 63;
    const int w = t >> 6;
    const int wrb = (w >> 1) * 64, wcb = (w & 1) * 64;
    const int l15 = l & 15, lg = l >> 4;

    f32x4 acc[4][4];
    #pragma unroll
    for (int i = 0; i < 4; i++)
        #pragma unroll
        for (int j = 0; j < 4; j++) acc[i][j] = (f32x4)0.f;

    for (int k0 = 0; k0 < K; k0 += 32) {
        #pragma unroll
        for (int i = 0; i < 2; i++) {
            const int chunk = i * 256 + t;
            const int row = chunk >> 2, c8 = (chunk & 3) * 8;
            GLD16(A  + (size_t)(bm + row) * K + k0 + c8, As + chunk * 8);
            GLD16(Bt + (size_t)(bn + row) * K + k0 + c8, Bs + chunk * 8);
        }
        __syncthreads();

        short8 af[4], bfr[4];
        #pragma unroll
        for (int f = 0; f < 4; f++) {
            af[f]  = *(const short8*)(As + (wrb + f * 16 + l15) * 32 + lg * 8);
            bfr[f] = *(const short8*)(Bs + (wcb + f * 16 + l15) * 32 + lg * 8);
        }
        #pragma unroll
        for (int fm = 0; fm < 4; fm++)
            #pragma unroll
            for (int fn = 0; fn < 4; fn++)
                acc[fm][fn] = __builtin_amdgcn_mfma_f32_16x16x32_bf16(
                    af[fm], bfr[fn], acc[fm][fn], 0, 0, 0);
        __syncthreads();
    }

    // epilogue: C/D layout col = lane&15, row = (lane>>4)*4 + j
    #pragma unroll
    for (int fn = 0; fn < 4; fn++) {
        const int col = bn + wcb + fn * 16 + l15;
        if (col >= N) continue;
        const float bi = bias ? bias[col] : 0.f;
        #pragma unroll
        for (int fm = 0; fm < 4; fm++) {
            #pragma unroll
            for (int j = 0; j < 4; j++) {
                const int row = bm + wrb + fm * 16 + lg * 4 + j;
                float v = acc[fm][fn][j] + bi;
                if (ACT == 1) {
                    float u = 0.7978845608028654f * (v + 0.044715f * v * v * v);
                    v = 0.5f * v * (1.f + tanhf(u));
                }
                if (HASADD) v += addsrc[(size_t)row * N + col];
                if (OUTBF) ((ushort*)Cout)[(size_t)row * N + col] = f2bf(v);
                else       ((float*) Cout)[(size_t)row * N + col] = v;
            }
        }
    }
}

// ---------------------------------------------------------------------------
// Causal attention, bf16 qkv input, bf16 o output. One block per (q, head).
// ---------------------------------------------------------------------------
__global__ __launch_bounds__(256) void attn_bf(const ushort* __restrict__ qkv,
                                               ushort* __restrict__ o) {
    const int q = blockIdx.x;
    const int h = blockIdx.y;
    const int tid = threadIdx.x;

    __shared__ float qrow[HEADD];
    __shared__ float sc[NCTX];
    __shared__ float red[256];
    __shared__ float part[4][HEADD];

    if (tid < HEADD) qrow[tid] = bf2f(qkv[(size_t)q * D3 + h * HEADD + tid]);
    __syncthreads();

    const float scale = 0.125f;

    float lmax = -1e30f;
    for (int k = tid; k <= q; k += 256) {
        const ushort* kr = qkv + (size_t)k * D3 + DMODEL + h * HEADD;
        const short8* kv8 = (const short8*)kr;
        float s = 0.f;
        #pragma unroll
        for (int c = 0; c < 8; c++) {
            short8 v = kv8[c];
            #pragma unroll
            for (int j = 0; j < 8; j++) s += qrow[c * 8 + j] * bf2f((ushort)v[j]);
        }
        s *= scale;
        sc[k] = s;
        lmax = fmaxf(lmax, s);
    }
    red[tid] = lmax; __syncthreads();
    for (int off = 128; off > 0; off >>= 1) {
        if (tid < off) red[tid] = fmaxf(red[tid], red[tid + off]);
        __syncthreads();
    }
    const float m = red[0];
    __syncthreads();

    float lsum = 0.f;
    for (int k = tid; k <= q; k += 256) {
        float p = expf(sc[k] - m);
        sc[k] = p;
        lsum += p;
    }
    red[tid] = lsum; __syncthreads();
    for (int off = 128; off > 0; off >>= 1) {
        if (tid < off) red[tid] += red[tid + off];
        __syncthreads();
    }
    const float inv = 1.f / red[0];

    const int grp = tid >> 6;
    const int d = tid & 63;
    float acc = 0.f;
    for (int k = grp; k <= q; k += 4)
        acc += sc[k] * bf2f(qkv[(size_t)k * D3 + 2 * DMODEL + h * HEADD + d]);
    part[grp][d] = acc;
    __syncthreads();

    if (tid < HEADD) {
        float v = (part[0][tid] + part[1][tid] + part[2][tid] + part[3][tid]) * inv;
        o[(size_t)q * DMODEL + h * HEADD + tid] = f2bf(v);
    }
}

// ===========================================================================
// Fallback f32 path (round-1 kernels), used only if ws is too small.
// ===========================================================================
#define BM 64
#define BN 64
#define BK 16
__global__ __launch_bounds__(256)
void gemm_f32(const float* __restrict__ A, const float* __restrict__ B,
              const float* __restrict__ bias, const float* __restrict__ addsrc,
              float* __restrict__ C, int M, int N, int K, int act) {
    __shared__ float As[BK][BM];
    __shared__ float Bs[BK][BN];
    const int bm = blockIdx.y * BM;
    const int bn = blockIdx.x * BN;
    const int tid = threadIdx.x;
    const int tr = tid >> 4;
    const int tc = tid & 15;
    float acc[4][4] = {};
    for (int k0 = 0; k0 < K; k0 += BK) {
        #pragma unroll
        for (int i = 0; i < 4; i++) {
            int idx = tid + i * 256;
            int row = idx >> 4, col = idx & 15;
            int gm = bm + row;
            float v = 0.f;
            if (gm < M) v = A[(size_t)gm * K + (k0 + col)];
            As[col][row] = v;
        }
        #pragma unroll
        for (int i = 0; i < 4; i++) {
            int idx = tid + i * 256;
            int row = idx >> 6, col = idx & 63;
            int gn = bn + col;
            float v = 0.f;
            if (gn < N) v = B[(size_t)(k0 + row) * N + gn];
            Bs[row][col] = v;
        }
        __syncthreads();
        #pragma unroll
        for (int kk = 0; kk < BK; kk++) {
            float a[4], bb[4];
            #pragma unroll
            for (int i = 0; i < 4; i++) a[i] = As[kk][tr * 4 + i];
            #pragma unroll
            for (int j = 0; j < 4; j++) bb[j] = Bs[kk][tc * 4 + j];
            #pragma unroll
            for (int i = 0; i < 4; i++)
                #pragma unroll
                for (int j = 0; j < 4; j++)
                    acc[i][j] += a[i] * bb[j];
        }
        __syncthreads();
    }
    #pragma unroll
    for (int i = 0; i < 4; i++) {
        int gm = bm + tr * 4 + i;
        if (gm >= M) continue;
        #pragma unroll
        for (int j = 0; j < 4; j++) {
            int gn = bn + tc * 4 + j;
            if (gn >= N) continue;
            float v = acc[i][j] + (bias ? bias[gn] : 0.f);
            if (act == 1) {
                const float cst = 0.7978845608028654f;
                float t = tanhf(cst * (v + 0.044715f * v * v * v));
                v = 0.5f * v * (1.f + t);
            }
            if (addsrc) v += addsrc[(size_t)gm * N + gn];
            C[(size_t)gm * N + gn] = v;
        }
    }
}

__global__ __launch_bounds__(256)
void attn_k(const float* __restrict__ qkv, float* __restrict__ o) {
    const int q = blockIdx.x;
    const int h = blockIdx.y;
    const int tid = threadIdx.x;
    __shared__ float qrow[HEADD];
    __shared__ float sc[NCTX];
    __shared__ float red[256];
    __shared__ float part[4][HEADD];
    if (tid < HEADD) qrow[tid] = qkv[(size_t)q * D3 + h * HEADD + tid];
    __syncthreads();
    const float scale = 0.125f;
    float lmax = -1e30f;
    for (int k = tid; k <= q; k += 256) {
        const float* kr = qkv + (size_t)k * D3 + DMODEL + h * HEADD;
        float s = 0.f;
        #pragma unroll
        for (int d = 0; d < HEADD; d++) s += qrow[d] * kr[d];
        s *= scale;
        sc[k] = s;
        lmax = fmaxf(lmax, s);
    }
    red[tid] = lmax; __syncthreads();
    for (int off = 128; off > 0; off >>= 1) {
        if (tid < off) red[tid] = fmaxf(red[tid], red[tid + off]);
        __syncthreads();
    }
    const float m = red[0];
    __syncthreads();
    float lsum = 0.f;
    for (int k = tid; k <= q; k += 256) {
        float p = expf(sc[k] - m);
        sc[k] = p;
        lsum += p;
    }
    red[tid] = lsum; __syncthreads();
    for (int off = 128; off > 0; off >>= 1) {
        if (tid < off) red[tid] += red[tid + off];
        __syncthreads();
    }
    const float inv = 1.f / red[0];
    const int grp = tid >> 6;
    const int d = tid & 63;
    float acc = 0.f;
    for (int k = grp; k <= q; k += 4)
        acc += sc[k] * qkv[(size_t)k * D3 + 2 * DMODEL + h * HEADD + d];
    part[grp][d] = acc;
    __syncthreads();
    if (tid < HEADD) {
        float v = (part[0][tid] + part[1][tid] + part[2][tid] + part[3][tid]) * inv;
        o[(size_t)q * DMODEL + h * HEADD + tid] = v;
    }
}

// ---------------------------------------------------------------------------
// Launch
// ---------------------------------------------------------------------------
extern "C" void kernel_launch(void* const* d_in, const int* in_sizes, int n_in,
                              void* d_out, int out_size, void* d_ws, size_t ws_size,
                              hipStream_t stream) {
    const int*   tokens      = (const int*)  d_in[0];
    const float* vocab_embed = (const float*)d_in[1];
    const float* pos_embed   = (const float*)d_in[2];
    const float* ln1_g       = (const float*)d_in[3];
    const float* ln1_b       = (const float*)d_in[4];
    const float* att_w       = (const float*)d_in[5];
    const float* att_b       = (const float*)d_in[6];
    const float* attn_proj_w = (const float*)d_in[7];
    const float* attn_proj_b = (const float*)d_in[8];
    const float* ln2_g       = (const float*)d_in[9];
    const float* ln2_b       = (const float*)d_in[10];
    const float* fc_w        = (const float*)d_in[11];
    const float* fc_b        = (const float*)d_in[12];
    const float* mlp_proj_w  = (const float*)d_in[13];
    const float* mlp_proj_b  = (const float*)d_in[14];
    const float* lnf_g       = (const float*)d_in[15];
    const float* lnf_b       = (const float*)d_in[16];
    const float* out_w       = (const float*)d_in[17];
    const float* out_b       = (const float*)d_in[18];
    float* out = (float*)d_out;

    const int C = NCTX;
    dim3 blk(256);

    // ---- workspace carve (256B aligned) for the bf16 path ----
    char* wp = (char*)d_ws;
    size_t used = 0;
    auto carve = [&](size_t bytes) -> void* {
        bytes = (bytes + 255) & ~(size_t)255;
        void* p = wp + used;
        used += bytes;
        return p;
    };
    float*  x_f    = (float*) carve((size_t)C * DMODEL * 4);
    float*  h_f    = (float*) carve((size_t)C * DMODEL * 4);
    ushort* h_bf   = (ushort*)carve((size_t)C * DMODEL * 2);
    ushort* qkv_bf = (ushort*)carve((size_t)C * D3 * 2);
    ushort* o_bf   = (ushort*)carve((size_t)C * DMODEL * 2);
    ushort* mid_bf = (ushort*)carve((size_t)C * D4 * 2);
    ushort* wt_a   = (ushort*)carve((size_t)D3 * DMODEL * 2);
    ushort* wt_p   = (ushort*)carve((size_t)DMODEL * DMODEL * 2);
    ushort* wt_f   = (ushort*)carve((size_t)D4 * DMODEL * 2);
    ushort* wt_m   = (ushort*)carve((size_t)DMODEL * D4 * 2);
    ushort* wt_out = (ushort*)carve((size_t)NVPAD * DMODEL * 2);

    if (ws_size >= used) {
        // ================= bf16 MFMA path =================
        // out_w^T -> bf16 [NVPAD][768]
        transp_bf16<<<dim3(NVPAD / 32, DMODEL / 32), blk, 0, stream>>>(
            out_w, wt_out, DMODEL, NVOCAB);

        embed_k<<<dim3(C), blk, 0, stream>>>(tokens, vocab_embed, pos_embed, x_f);

        for (int l = 0; l < LAYERS; l++) {
            // weight transposes for this layer
            transp_bf16<<<dim3(D3 / 32, DMODEL / 32), blk, 0, stream>>>(
                att_w + (size_t)l * DMODEL * D3, wt_a, DMODEL, D3);
            transp_bf16<<<dim3(DMODEL / 32, DMODEL / 32), blk, 0, stream>>>(
                attn_proj_w + (size_t)l * DMODEL * DMODEL, wt_p, DMODEL, DMODEL);
            transp_bf16<<<dim3(D4 / 32, DMODEL / 32), blk, 0, stream>>>(
                fc_w + (size_t)l * DMODEL * D4, wt_f, DMODEL, D4);
            transp_bf16<<<dim3(DMODEL / 32, D4 / 32), blk, 0, stream>>>(
                mlp_proj_w + (size_t)l * D4 * DMODEL, wt_m, D4, DMODEL);

            // h = LN1(x) -> f32 + bf16
            layernorm_k<<<dim3(C), blk, 0, stream>>>(
                x_f, ln1_g + l * DMODEL, ln1_b + l * DMODEL, h_f, h_bf);

            // qkv = h @ att_w + att_b   (bf16 out)
            gemm_bf16<0, false, true><<<dim3(D3 / 128, C / 128), blk, 0, stream>>>(
                h_bf, wt_a, att_b + l * D3, nullptr, qkv_bf, D3, DMODEL);

            // o = attention(qkv)  (bf16 out)
            attn_bf<<<dim3(C, NHEAD), blk, 0, stream>>>(qkv_bf, o_bf);

            // x = h + o @ attn_proj_w + attn_proj_b  (f32 out)
            gemm_bf16<0, true, false><<<dim3(DMODEL / 128, C / 128), blk, 0, stream>>>(
                o_bf, wt_p, attn_proj_b + l * DMODEL, h_f, x_f, DMODEL, DMODEL);

            // h2 = LN2(x)
            layernorm_k<<<dim3(C), blk, 0, stream>>>(
                x_f, ln2_g + l * DMODEL, ln2_b + l * DMODEL, h_f, h_bf);

            // mid = gelu(h2 @ fc_w + fc_b)  (bf16 out)
            gemm_bf16<1, false, true><<<dim3(D4 / 128, C / 128), blk, 0, stream>>>(
                h_bf, wt_f, fc_b + l * D4, nullptr, mid_bf, D4, DMODEL);

            // x = h2 + mid @ mlp_proj_w + mlp_proj_b  (f32 out)
            gemm_bf16<0, true, false><<<dim3(DMODEL / 128, C / 128), blk, 0, stream>>>(
                mid_bf, wt_m, mlp_proj_b + l * DMODEL, h_f, x_f, DMODEL, D4);
        }

        // final LN (only bf16 needed)
        layernorm_k<<<dim3(C), blk, 0, stream>>>(x_f, lnf_g, lnf_b, nullptr, h_bf);

        // logits = h @ out_w + out_b  (f32 out, N-guarded)
        gemm_bf16<0, false, false><<<dim3(NVPAD / 128, C / 128), blk, 0, stream>>>(
            h_bf, wt_out, out_b, nullptr, out, NVOCAB, DMODEL);
        return;
    }

    // ================= fallback f32 path =================
    const size_t n_x   = (size_t)C * DMODEL;
    const size_t n_qkv = (size_t)C * D3;
    const size_t n_mid = (size_t)C * D4;
    const size_t need_bytes = (3 * n_x + n_qkv + n_mid) * sizeof(float);

    float *x, *h, *o, *qkv, *mid;
    float* ws = (float*)d_ws;
    if (ws_size >= need_bytes) {
        x = ws; h = x + n_x; o = h + n_x; qkv = o + n_x; mid = qkv + n_qkv;
    } else {
        x = ws; h = x + n_x; o = h + n_x;
        qkv = (float*)d_out; mid = qkv + n_qkv;
    }

    embed_k<<<dim3(C), blk, 0, stream>>>(tokens, vocab_embed, pos_embed, x);
    for (int l = 0; l < LAYERS; l++) {
        const float* lw;
        layernorm_k<<<dim3(C), blk, 0, stream>>>(x, ln1_g + l * DMODEL, ln1_b + l * DMODEL, h, nullptr);
        lw = att_w + (size_t)l * DMODEL * D3;
        gemm_f32<<<dim3(D3 / BN, C / BM), blk, 0, stream>>>(
            h, lw, att_b + l * D3, nullptr, qkv, C, D3, DMODEL, 0);
        attn_k<<<dim3(C, NHEAD), blk, 0, stream>>>(qkv, o);
        lw = attn_proj_w + (size_t)l * DMODEL * DMODEL;
        gemm_f32<<<dim3(DMODEL / BN, C / BM), blk, 0, stream>>>(
            o, lw, attn_proj_b + l * DMODEL, h, x, C, DMODEL, DMODEL, 0);
        layernorm_k<<<dim3(C), blk, 0, stream>>>(x, ln2_g + l * DMODEL, ln2_b + l * DMODEL, h, nullptr);
        lw = fc_w + (size_t)l * DMODEL * D4;
        gemm_f32<<<dim3(D4 / BN, C / BM), blk, 0, stream>>>(
            h, lw, fc_b + l * D4, nullptr, mid, C, D4, DMODEL, 1);
        lw = mlp_proj_w + (size_t)l * D4 * DMODEL;
        gemm_f32<<<dim3(DMODEL / BN, C / BM), blk, 0, stream>>>(
            mid, lw, mlp_proj_b + l * DMODEL, h, x, C, DMODEL, D4, 0);
    }
    layernorm_k<<<dim3(C), blk, 0, stream>>>(x, lnf_g, lnf_b, h, nullptr);
    gemm_f32<<<dim3((NVOCAB + BN - 1) / BN, C / BM), blk, 0, stream>>>(
        h, out_w, out_b, nullptr, out, C, NVOCAB, DMODEL, 0);
}

// Round 3
// 1376.020 us; speedup vs baseline: 8.5042x; 3.6439x over previous
//
#include <hip/hip_runtime.h>
#include <hip/hip_bf16.h>
#include <math.h>

// Problem constants
#define LAYERS 4
#define NHEAD  12
#define DMODEL 768
#define HEADD  64
#define NCTX   2048
#define NVOCAB 50257
#define NVPAD  50304            // 393*128
#define D3     (3*DMODEL)
#define D4     (4*DMODEL)

typedef short short8 __attribute__((ext_vector_type(8)));
typedef float f32x4  __attribute__((ext_vector_type(4)));

__device__ __forceinline__ float bf2f(ushort u) {
    union { uint i; float f; } c; c.i = ((uint)u) << 16; return c.f;
}
__device__ __forceinline__ ushort f2bf(float f) {
    union { float f; uint i; } c; c.f = f;
    uint i = c.i;
    uint r = (i + 0x7FFFu + ((i >> 16) & 1u)) >> 16;   // round-nearest-even
    return (ushort)r;
}

#define GLD16(gp, lp) __builtin_amdgcn_global_load_lds( \
    (__attribute__((address_space(1))) void*)(gp),      \
    (__attribute__((address_space(3))) void*)(lp), 16, 0, 0)

// ---------------------------------------------------------------------------
// Embedding
// ---------------------------------------------------------------------------
__global__ void embed_k(const int* __restrict__ tok,
                        const float* __restrict__ ve,
                        const float* __restrict__ pe,
                        float* __restrict__ x) {
    int c = blockIdx.x;
    int t = tok[c];
    for (int d = threadIdx.x; d < DMODEL; d += blockDim.x)
        x[(size_t)c * DMODEL + d] = ve[(size_t)t * DMODEL + d] + pe[(size_t)c * DMODEL + d];
}

// ---------------------------------------------------------------------------
// LayerNorm, one block per row. Writes f32 (optional) and bf16 (optional).
// ---------------------------------------------------------------------------
__global__ void layernorm_k(const float* __restrict__ x,
                            const float* __restrict__ g,
                            const float* __restrict__ b,
                            float* __restrict__ yf,
                            ushort* __restrict__ ybf) {
    const int row = blockIdx.x;
    const float* xr = x + (size_t)row * DMODEL;
    __shared__ float red[256];
    const int tid = threadIdx.x;

    float s = 0.f;
    for (int d = tid; d < DMODEL; d += 256) s += xr[d];
    red[tid] = s; __syncthreads();
    for (int off = 128; off > 0; off >>= 1) {
        if (tid < off) red[tid] += red[tid + off];
        __syncthreads();
    }
    const float mu = red[0] / DMODEL;
    __syncthreads();

    float v = 0.f;
    for (int d = tid; d < DMODEL; d += 256) { float t = xr[d] - mu; v += t * t; }
    red[tid] = v; __syncthreads();
    for (int off = 128; off > 0; off >>= 1) {
        if (tid < off) red[tid] += red[tid + off];
        __syncthreads();
    }
    const float rstd = rsqrtf(red[0] / DMODEL + 1e-5f);

    for (int d = tid; d < DMODEL; d += 256) {
        float r = (xr[d] - mu) * rstd * g[d] + b[d];
        if (yf)  yf[(size_t)row * DMODEL + d] = r;
        if (ybf) ybf[(size_t)row * DMODEL + d] = f2bf(r);
    }
}

// ---------------------------------------------------------------------------
// Transpose + f32->bf16: src [K,N] f32 -> dst [Npad,K] bf16
// ---------------------------------------------------------------------------
__global__ __launch_bounds__(256) void transp_bf16(const float* __restrict__ src,
                                                   ushort* __restrict__ dst,
                                                   int K, int N) {
    __shared__ float tile[32][33];
    const int nt = blockIdx.x * 32, kt = blockIdx.y * 32;
    const int t = threadIdx.x;
    const int lr = t >> 5, lc = t & 31;

    #pragma unroll
    for (int i = 0; i < 4; i++) {
        int k = kt + lr + i * 8, n = nt + lc;
        float v = (n < N) ? src[(size_t)k * N + n] : 0.f;
        tile[lr + i * 8][lc] = v;
    }
    __syncthreads();
    #pragma unroll
    for (int i = 0; i < 4; i++) {
        int n = nt + lr + i * 8, k = kt + lc;
        dst[(size_t)n * K + k] = f2bf(tile[lc][lr + i * 8]);
    }
}

// ---------------------------------------------------------------------------
// bf16 MFMA GEMM. A [M,K] bf16 row-major, Bt [Npad,K] bf16 (B transposed).
// 128x128 tile, BK=32, 256 thr, 4 waves. ACT: 0 none, 1 GELU. OUTBF: bf16 out.
// ---------------------------------------------------------------------------
template<int ACT, bool HASADD, bool OUTBF>
__global__ __launch_bounds__(256) void gemm_bf16(
    const ushort* __restrict__ A, const ushort* __restrict__ Bt,
    const float* __restrict__ bias, const float* __restrict__ addsrc,
    void* __restrict__ Cout, int N, int K)
{
    __shared__ __align__(16) ushort As[128 * 32];
    __shared__ __align__(16) ushort Bs[128 * 32];
    const int bm = blockIdx.y * 128, bn = blockIdx.x * 128;
    const int t = threadIdx.x, l = t & 63;
    const int w = t >> 6;
    const int wrb = (w >> 1) * 64, wcb = (w & 1) * 64;
    const int l15 = l & 15, lg = l >> 4;

    f32x4 acc[4][4];
    #pragma unroll
    for (int i = 0; i < 4; i++)
        #pragma unroll
        for (int j = 0; j < 4; j++) acc[i][j] = (f32x4)0.f;

    for (int k0 = 0; k0 < K; k0 += 32) {
        #pragma unroll
        for (int i = 0; i < 2; i++) {
            const int chunk = i * 256 + t;
            const int row = chunk >> 2, c8 = (chunk & 3) * 8;
            GLD16(A  + (size_t)(bm + row) * K + k0 + c8, As + chunk * 8);
            GLD16(Bt + (size_t)(bn + row) * K + k0 + c8, Bs + chunk * 8);
        }
        __syncthreads();

        short8 af[4], bfr[4];
        #pragma unroll
        for (int f = 0; f < 4; f++) {
            af[f]  = *(const short8*)(As + (wrb + f * 16 + l15) * 32 + lg * 8);
            bfr[f] = *(const short8*)(Bs + (wcb + f * 16 + l15) * 32 + lg * 8);
        }
        #pragma unroll
        for (int fm = 0; fm < 4; fm++)
            #pragma unroll
            for (int fn = 0; fn < 4; fn++)
                acc[fm][fn] = __builtin_amdgcn_mfma_f32_16x16x32_bf16(
                    af[fm], bfr[fn], acc[fm][fn], 0, 0, 0);
        __syncthreads();
    }

    #pragma unroll
    for (int fn = 0; fn < 4; fn++) {
        const int col = bn + wcb + fn * 16 + l15;
        if (col >= N) continue;
        const float bi = bias ? bias[col] : 0.f;
        #pragma unroll
        for (int fm = 0; fm < 4; fm++) {
            #pragma unroll
            for (int j = 0; j < 4; j++) {
                const int row = bm + wrb + fm * 16 + lg * 4 + j;
                float v = acc[fm][fn][j] + bi;
                if (ACT == 1) {
                    float u = 0.7978845608028654f * (v + 0.044715f * v * v * v);
                    v = 0.5f * v * (1.f + tanhf(u));
                }
                if (HASADD) v += addsrc[(size_t)row * N + col];
                if (OUTBF) ((ushort*)Cout)[(size_t)row * N + col] = f2bf(v);
                else       ((float*) Cout)[(size_t)row * N + col] = v;
            }
        }
    }
}

// ---------------------------------------------------------------------------
// MFMA flash attention. Block = (head, 64-row q-tile), 4 waves x 16 q rows.
// KV tiles of 64. K swizzled row-major in LDS; V transposed+swizzled.
// P converted C-layout -> A-layout via per-wave swizzled LDS buffer.
// ---------------------------------------------------------------------------
#define QBLK  64
#define KVBLK 64
__global__ __launch_bounds__(256) void attn_mfma(const ushort* __restrict__ qkv,
                                                 ushort* __restrict__ o) {
    const int h  = blockIdx.x;
    const int qt = (int)(gridDim.y - 1) - (int)blockIdx.y;   // heavy tiles first
    const int q0 = qt * QBLK;
    const int t = threadIdx.x;
    const int w = t >> 6;
    const int l = t & 63;
    const int l15 = l & 15, lg = l >> 4;

    __shared__ __align__(16) ushort Ks[KVBLK * HEADD];   // [kv][d], swizzled
    __shared__ __align__(16) ushort Vt[HEADD * KVBLK];   // [d][kv], swizzled
    __shared__ __align__(16) ushort Ps[4][16 * KVBLK];   // per-wave P, swizzled

    // Q fragments (A layout: row=l15, k=lg*8+j), rows q0 + w*16 + l15
    const int qrow = q0 + w * 16 + l15;
    short8 qf[2];
    #pragma unroll
    for (int s = 0; s < 2; s++)
        qf[s] = *(const short8*)(qkv + (size_t)qrow * D3 + h * HEADD + s * 32 + lg * 8);

    f32x4 Of[4];
    #pragma unroll
    for (int i = 0; i < 4; i++) Of[i] = (f32x4)0.f;
    float m_run[4], l_run[4];
    #pragma unroll
    for (int j = 0; j < 4; j++) { m_run[j] = -1e30f; l_run[j] = 0.f; }

    const float scale = 0.125f;   // 1/sqrt(64)
    const int ntiles = qt + 1;

    for (int kt = 0; kt < ntiles; kt++) {
        const int k0 = kt * KVBLK;
        __syncthreads();
        // ---- stage K tile: rows [k0,k0+64) x 64 d, swizzled ----
        #pragma unroll
        for (int i = 0; i < 2; i++) {
            int c = t + i * 256;              // 0..511
            int r = c >> 3, cb = (c & 7) * 16; // byte col
            short8 v = *(const short8*)(qkv + (size_t)(k0 + r) * D3 + DMODEL + h * HEADD + (c & 7) * 8);
            int addr = (r * 128 + cb) ^ ((r & 7) << 4);
            *(short8*)((char*)Ks + addr) = v;
        }
        // ---- stage V transposed: Vt[d][kv], swizzled ----
        #pragma unroll
        for (int i = 0; i < 2; i++) {
            int c = t + i * 256;
            int r = c >> 3, d0 = (c & 7) * 8;
            short8 v = *(const short8*)(qkv + (size_t)(k0 + r) * D3 + 2 * DMODEL + h * HEADD + d0);
            #pragma unroll
            for (int j2 = 0; j2 < 8; j2++) {
                int d = d0 + j2;
                int addr = (d * 128 + r * 2) ^ ((d & 7) << 4);
                *(ushort*)((char*)Vt + addr) = (ushort)v[j2];
            }
        }
        __syncthreads();

        // ---- S = Q @ K^T  (C layout: row=lg*4+j -> q, col=l15 -> kv) ----
        f32x4 S[4];
        #pragma unroll
        for (int nf = 0; nf < 4; nf++) {
            f32x4 a = (f32x4)0.f;
            #pragma unroll
            for (int s = 0; s < 2; s++) {
                int r = nf * 16 + l15;
                int addr = (r * 128 + s * 64 + lg * 16) ^ ((r & 7) << 4);
                short8 kf = *(const short8*)((char*)Ks + addr);
                a = __builtin_amdgcn_mfma_f32_16x16x32_bf16(qf[s], kf, a, 0, 0, 0);
            }
            S[nf] = a;
        }

        // ---- mask + online softmax ----
        float p[4][4];
        #pragma unroll
        for (int nf = 0; nf < 4; nf++) {
            int kvg = k0 + nf * 16 + l15;
            #pragma unroll
            for (int j = 0; j < 4; j++) {
                int qg = q0 + w * 16 + lg * 4 + j;
                p[nf][j] = (kvg <= qg) ? S[nf][j] * scale : -1e30f;
            }
        }
        #pragma unroll
        for (int j = 0; j < 4; j++) {
            float mx = fmaxf(fmaxf(p[0][j], p[1][j]), fmaxf(p[2][j], p[3][j]));
            mx = fmaxf(mx, __shfl_xor(mx, 1));
            mx = fmaxf(mx, __shfl_xor(mx, 2));
            mx = fmaxf(mx, __shfl_xor(mx, 4));
            mx = fmaxf(mx, __shfl_xor(mx, 8));
            float mnew = fmaxf(m_run[j], mx);
            float sc = __expf(m_run[j] - mnew);
            m_run[j] = mnew;
            float psum = 0.f;
            #pragma unroll
            for (int nf = 0; nf < 4; nf++) {
                float e = __expf(p[nf][j] - mnew);
                p[nf][j] = e;
                psum += e;
            }
            psum += __shfl_xor(psum, 1);
            psum += __shfl_xor(psum, 2);
            psum += __shfl_xor(psum, 4);
            psum += __shfl_xor(psum, 8);
            l_run[j] = l_run[j] * sc + psum;
            #pragma unroll
            for (int df = 0; df < 4; df++) Of[df][j] *= sc;
        }

        // ---- P: C-layout regs -> swizzled LDS (per wave) ----
        char* pw = (char*)&Ps[w][0];
        #pragma unroll
        for (int nf = 0; nf < 4; nf++)
            #pragma unroll
            for (int j = 0; j < 4; j++) {
                int ql = lg * 4 + j;
                int addr = (ql * 128 + (nf * 16 + l15) * 2) ^ ((ql & 7) << 4);
                *(ushort*)(pw + addr) = f2bf(p[nf][j]);
            }

        // ---- O += P @ V ----
        #pragma unroll
        for (int s = 0; s < 2; s++) {
            int paddr = (l15 * 128 + s * 64 + lg * 16) ^ ((l15 & 7) << 4);
            short8 pf = *(const short8*)(pw + paddr);
            #pragma unroll
            for (int df = 0; df < 4; df++) {
                int r = df * 16 + l15;
                int vaddr = (r * 128 + s * 64 + lg * 16) ^ ((r & 7) << 4);
                short8 vf = *(const short8*)((char*)Vt + vaddr);
                Of[df] = __builtin_amdgcn_mfma_f32_16x16x32_bf16(pf, vf, Of[df], 0, 0, 0);
            }
        }
    }

    // ---- epilogue ----
    #pragma unroll
    for (int j = 0; j < 4; j++) {
        float inv = 1.f / l_run[j];
        int qg = q0 + w * 16 + lg * 4 + j;
        #pragma unroll
        for (int df = 0; df < 4; df++)
            o[(size_t)qg * DMODEL + h * HEADD + df * 16 + l15] = f2bf(Of[df][j] * inv);
    }
}

// ===========================================================================
// Fallback f32 path (only if ws too small)
// ===========================================================================
#define BM 64
#define BN 64
#define BK 16
__global__ __launch_bounds__(256)
void gemm_f32(const float* __restrict__ A, const float* __restrict__ B,
              const float* __restrict__ bias, const float* __restrict__ addsrc,
              float* __restrict__ C, int M, int N, int K, int act) {
    __shared__ float As[BK][BM];
    __shared__ float Bs[BK][BN];
    const int bm = blockIdx.y * BM;
    const int bn = blockIdx.x * BN;
    const int tid = threadIdx.x;
    const int tr = tid >> 4;
    const int tc = tid & 15;
    float acc[4][4] = {};
    for (int k0 = 0; k0 < K; k0 += BK) {
        #pragma unroll
        for (int i = 0; i < 4; i++) {
            int idx = tid + i * 256;
            int row = idx >> 4, col = idx & 15;
            int gm = bm + row;
            float v = 0.f;
            if (gm < M) v = A[(size_t)gm * K + (k0 + col)];
            As[col][row] = v;
        }
        #pragma unroll
        for (int i = 0; i < 4; i++) {
            int idx = tid + i * 256;
            int row = idx >> 6, col = idx & 63;
            int gn = bn + col;
            float v = 0.f;
            if (gn < N) v = B[(size_t)(k0 + row) * N + gn];
            Bs[row][col] = v;
        }
        __syncthreads();
        #pragma unroll
        for (int kk = 0; kk < BK; kk++) {
            float a[4], bb[4];
            #pragma unroll
            for (int i = 0; i < 4; i++) a[i] = As[kk][tr * 4 + i];
            #pragma unroll
            for (int j = 0; j < 4; j++) bb[j] = Bs[kk][tc * 4 + j];
            #pragma unroll
            for (int i = 0; i < 4; i++)
                #pragma unroll
                for (int j = 0; j < 4; j++)
                    acc[i][j] += a[i] * bb[j];
        }
        __syncthreads();
    }
    #pragma unroll
    for (int i = 0; i < 4; i++) {
        int gm = bm + tr * 4 + i;
        if (gm >= M) continue;
        #pragma unroll
        for (int j = 0; j < 4; j++) {
            int gn = bn + tc * 4 + j;
            if (gn >= N) continue;
            float v = acc[i][j] + (bias ? bias[gn] : 0.f);
            if (act == 1) {
                const float cst = 0.7978845608028654f;
                float t = tanhf(cst * (v + 0.044715f * v * v * v));
                v = 0.5f * v * (1.f + t);
            }
            if (addsrc) v += addsrc[(size_t)gm * N + gn];
            C[(size_t)gm * N + gn] = v;
        }
    }
}

__global__ __launch_bounds__(256)
void attn_k(const float* __restrict__ qkv, float* __restrict__ o) {
    const int q = blockIdx.x;
    const int h = blockIdx.y;
    const int tid = threadIdx.x;
    __shared__ float qrow[HEADD];
    __shared__ float sc[NCTX];
    __shared__ float red[256];
    __shared__ float part[4][HEADD];
    if (tid < HEADD) qrow[tid] = qkv[(size_t)q * D3 + h * HEADD + tid];
    __syncthreads();
    const float scale = 0.125f;
    float lmax = -1e30f;
    for (int k = tid; k <= q; k += 256) {
        const float* kr = qkv + (size_t)k * D3 + DMODEL + h * HEADD;
        float s = 0.f;
        #pragma unroll
        for (int d = 0; d < HEADD; d++) s += qrow[d] * kr[d];
        s *= scale;
        sc[k] = s;
        lmax = fmaxf(lmax, s);
    }
    red[tid] = lmax; __syncthreads();
    for (int off = 128; off > 0; off >>= 1) {
        if (tid < off) red[tid] = fmaxf(red[tid], red[tid + off]);
        __syncthreads();
    }
    const float m = red[0];
    __syncthreads();
    float lsum = 0.f;
    for (int k = tid; k <= q; k += 256) {
        float p = expf(sc[k] - m);
        sc[k] = p;
        lsum += p;
    }
    red[tid] = lsum; __syncthreads();
    for (int off = 128; off > 0; off >>= 1) {
        if (tid < off) red[tid] += red[tid + off];
        __syncthreads();
    }
    const float inv = 1.f / red[0];
    const int grp = tid >> 6;
    const int d = tid & 63;
    float acc = 0.f;
    for (int k = grp; k <= q; k += 4)
        acc += sc[k] * qkv[(size_t)k * D3 + 2 * DMODEL + h * HEADD + d];
    part[grp][d] = acc;
    __syncthreads();
    if (tid < HEADD) {
        float v = (part[0][tid] + part[1][tid] + part[2][tid] + part[3][tid]) * inv;
        o[(size_t)q * DMODEL + h * HEADD + tid] = v;
    }
}

// ---------------------------------------------------------------------------
// Launch
// ---------------------------------------------------------------------------
extern "C" void kernel_launch(void* const* d_in, const int* in_sizes, int n_in,
                              void* d_out, int out_size, void* d_ws, size_t ws_size,
                              hipStream_t stream) {
    const int*   tokens      = (const int*)  d_in[0];
    const float* vocab_embed = (const float*)d_in[1];
    const float* pos_embed   = (const float*)d_in[2];
    const float* ln1_g       = (const float*)d_in[3];
    const float* ln1_b       = (const float*)d_in[4];
    const float* att_w       = (const float*)d_in[5];
    const float* att_b       = (const float*)d_in[6];
    const float* attn_proj_w = (const float*)d_in[7];
    const float* attn_proj_b = (const float*)d_in[8];
    const float* ln2_g       = (const float*)d_in[9];
    const float* ln2_b       = (const float*)d_in[10];
    const float* fc_w        = (const float*)d_in[11];
    const float* fc_b        = (const float*)d_in[12];
    const float* mlp_proj_w  = (const float*)d_in[13];
    const float* mlp_proj_b  = (const float*)d_in[14];
    const float* lnf_g       = (const float*)d_in[15];
    const float* lnf_b       = (const float*)d_in[16];
    const float* out_w       = (const float*)d_in[17];
    const float* out_b       = (const float*)d_in[18];
    float* out = (float*)d_out;

    const int C = NCTX;
    dim3 blk(256);

    // ---- workspace carve for bf16 path ----
    char* wp = (char*)d_ws;
    size_t used = 0;
    auto carve = [&](size_t bytes) -> void* {
        bytes = (bytes + 255) & ~(size_t)255;
        void* p = wp + used;
        used += bytes;
        return p;
    };
    float*  x_f    = (float*) carve((size_t)C * DMODEL * 4);
    float*  h_f    = (float*) carve((size_t)C * DMODEL * 4);
    ushort* h_bf   = (ushort*)carve((size_t)C * DMODEL * 2);
    ushort* qkv_bf = (ushort*)carve((size_t)C * D3 * 2);
    ushort* o_bf   = (ushort*)carve((size_t)C * DMODEL * 2);
    ushort* mid_bf = (ushort*)carve((size_t)C * D4 * 2);
    ushort* wt_a   = (ushort*)carve((size_t)D3 * DMODEL * 2);
    ushort* wt_p   = (ushort*)carve((size_t)DMODEL * DMODEL * 2);
    ushort* wt_f   = (ushort*)carve((size_t)D4 * DMODEL * 2);
    ushort* wt_m   = (ushort*)carve((size_t)DMODEL * D4 * 2);
    ushort* wt_out = (ushort*)carve((size_t)NVPAD * DMODEL * 2);

    if (ws_size >= used) {
        // ================= bf16 MFMA path =================
        transp_bf16<<<dim3(NVPAD / 32, DMODEL / 32), blk, 0, stream>>>(
            out_w, wt_out, DMODEL, NVOCAB);

        embed_k<<<dim3(C), blk, 0, stream>>>(tokens, vocab_embed, pos_embed, x_f);

        for (int l = 0; l < LAYERS; l++) {
            transp_bf16<<<dim3(D3 / 32, DMODEL / 32), blk, 0, stream>>>(
                att_w + (size_t)l * DMODEL * D3, wt_a, DMODEL, D3);
            transp_bf16<<<dim3(DMODEL / 32, DMODEL / 32), blk, 0, stream>>>(
                attn_proj_w + (size_t)l * DMODEL * DMODEL, wt_p, DMODEL, DMODEL);
            transp_bf16<<<dim3(D4 / 32, DMODEL / 32), blk, 0, stream>>>(
                fc_w + (size_t)l * DMODEL * D4, wt_f, DMODEL, D4);
            transp_bf16<<<dim3(DMODEL / 32, D4 / 32), blk, 0, stream>>>(
                mlp_proj_w + (size_t)l * D4 * DMODEL, wt_m, D4, DMODEL);

            layernorm_k<<<dim3(C), blk, 0, stream>>>(
                x_f, ln1_g + l * DMODEL, ln1_b + l * DMODEL, h_f, h_bf);

            gemm_bf16<0, false, true><<<dim3(D3 / 128, C / 128), blk, 0, stream>>>(
                h_bf, wt_a, att_b + l * D3, nullptr, qkv_bf, D3, DMODEL);

            attn_mfma<<<dim3(NHEAD, C / QBLK), blk, 0, stream>>>(qkv_bf, o_bf);

            gemm_bf16<0, true, false><<<dim3(DMODEL / 128, C / 128), blk, 0, stream>>>(
                o_bf, wt_p, attn_proj_b + l * DMODEL, h_f, x_f, DMODEL, DMODEL);

            layernorm_k<<<dim3(C), blk, 0, stream>>>(
                x_f, ln2_g + l * DMODEL, ln2_b + l * DMODEL, h_f, h_bf);

            gemm_bf16<1, false, true><<<dim3(D4 / 128, C / 128), blk, 0, stream>>>(
                h_bf, wt_f, fc_b + l * D4, nullptr, mid_bf, D4, DMODEL);

            gemm_bf16<0, true, false><<<dim3(DMODEL / 128, C / 128), blk, 0, stream>>>(
                mid_bf, wt_m, mlp_proj_b + l * DMODEL, h_f, x_f, DMODEL, D4);
        }

        layernorm_k<<<dim3(C), blk, 0, stream>>>(x_f, lnf_g, lnf_b, nullptr, h_bf);

        gemm_bf16<0, false, false><<<dim3(NVPAD / 128, C / 128), blk, 0, stream>>>(
            h_bf, wt_out, out_b, nullptr, out, NVOCAB, DMODEL);
        return;
    }

    // ================= fallback f32 path =================
    const size_t n_x   = (size_t)C * DMODEL;
    const size_t n_qkv = (size_t)C * D3;
    const size_t need_bytes = (3 * n_x + n_qkv + (size_t)C * D4) * sizeof(float);

    float *x, *h, *o, *qkv, *mid;
    float* ws = (float*)d_ws;
    if (ws_size >= need_bytes) {
        x = ws; h = x + n_x; o = h + n_x; qkv = o + n_x; mid = qkv + n_qkv;
    } else {
        x = ws; h = x + n_x; o = h + n_x;
        qkv = (float*)d_out; mid = qkv + n_qkv;
    }

    embed_k<<<dim3(C), blk, 0, stream>>>(tokens, vocab_embed, pos_embed, x);
    for (int l = 0; l < LAYERS; l++) {
        const float* lw;
        layernorm_k<<<dim3(C), blk, 0, stream>>>(x, ln1_g + l * DMODEL, ln1_b + l * DMODEL, h, nullptr);
        lw = att_w + (size_t)l * DMODEL * D3;
        gemm_f32<<<dim3(D3 / BN, C / BM), blk, 0, stream>>>(
            h, lw, att_b + l * D3, nullptr, qkv, C, D3, DMODEL, 0);
        attn_k<<<dim3(C, NHEAD), blk, 0, stream>>>(qkv, o);
        lw = attn_proj_w + (size_t)l * DMODEL * DMODEL;
        gemm_f32<<<dim3(DMODEL / BN, C / BM), blk, 0, stream>>>(
            o, lw, attn_proj_b + l * DMODEL, h, x, C, DMODEL, DMODEL, 0);
        layernorm_k<<<dim3(C), blk, 0, stream>>>(x, ln2_g + l * DMODEL, ln2_b + l * DMODEL, h, nullptr);
        lw = fc_w + (size_t)l * DMODEL * D4;
        gemm_f32<<<dim3(D4 / BN, C / BM), blk, 0, stream>>>(
            h, lw, fc_b + l * D4, nullptr, mid, C, D4, DMODEL, 1);
        lw = mlp_proj_w + (size_t)l * D4 * DMODEL;
        gemm_f32<<<dim3(DMODEL / BN, C / BM), blk, 0, stream>>>(
            mid, lw, mlp_proj_b + l * DMODEL, h, x, C, DMODEL, D4, 0);
    }
    layernorm_k<<<dim3(C), blk, 0, stream>>>(x, lnf_g, lnf_b, h, nullptr);
    gemm_f32<<<dim3((NVOCAB + BN - 1) / BN, C / BM), blk, 0, stream>>>(
        h, out_w, out_b, nullptr, out, C, NVOCAB, DMODEL, 0);
}

// Round 4
// 1263.338 us; speedup vs baseline: 9.2627x; 1.0892x over previous
//
#include <hip/hip_runtime.h>
#include <hip/hip_bf16.h>
#include <math.h>

// Problem constants
#define LAYERS 4
#define NHEAD  12
#define DMODEL 768
#define HEADD  64
#define NCTX   2048
#define NVOCAB 50257
#define NVPAD  50304            // 393*128
#define D3     (3*DMODEL)
#define D4     (4*DMODEL)

typedef short short8 __attribute__((ext_vector_type(8)));
typedef float f32x4  __attribute__((ext_vector_type(4)));

__device__ __forceinline__ float bf2f(ushort u) {
    union { uint i; float f; } c; c.i = ((uint)u) << 16; return c.f;
}
__device__ __forceinline__ ushort f2bf(float f) {
    union { float f; uint i; } c; c.f = f;
    uint i = c.i;
    uint r = (i + 0x7FFFu + ((i >> 16) & 1u)) >> 16;   // round-nearest-even
    return (ushort)r;
}

#define GLD16(gp, lp) __builtin_amdgcn_global_load_lds( \
    (__attribute__((address_space(1))) void*)(gp),      \
    (__attribute__((address_space(3))) void*)(lp), 16, 0, 0)

// ---------------------------------------------------------------------------
// Embedding
// ---------------------------------------------------------------------------
__global__ void embed_k(const int* __restrict__ tok,
                        const float* __restrict__ ve,
                        const float* __restrict__ pe,
                        float* __restrict__ x) {
    int c = blockIdx.x;
    int t = tok[c];
    for (int d = threadIdx.x; d < DMODEL; d += blockDim.x)
        x[(size_t)c * DMODEL + d] = ve[(size_t)t * DMODEL + d] + pe[(size_t)c * DMODEL + d];
}

// ---------------------------------------------------------------------------
// LayerNorm, one block per row. Writes f32 (optional) and bf16 (optional).
// ---------------------------------------------------------------------------
__global__ void layernorm_k(const float* __restrict__ x,
                            const float* __restrict__ g,
                            const float* __restrict__ b,
                            float* __restrict__ yf,
                            ushort* __restrict__ ybf) {
    const int row = blockIdx.x;
    const float* xr = x + (size_t)row * DMODEL;
    __shared__ float red[256];
    const int tid = threadIdx.x;

    float s = 0.f;
    for (int d = tid; d < DMODEL; d += 256) s += xr[d];
    red[tid] = s; __syncthreads();
    for (int off = 128; off > 0; off >>= 1) {
        if (tid < off) red[tid] += red[tid + off];
        __syncthreads();
    }
    const float mu = red[0] / DMODEL;
    __syncthreads();

    float v = 0.f;
    for (int d = tid; d < DMODEL; d += 256) { float t = xr[d] - mu; v += t * t; }
    red[tid] = v; __syncthreads();
    for (int off = 128; off > 0; off >>= 1) {
        if (tid < off) red[tid] += red[tid + off];
        __syncthreads();
    }
    const float rstd = rsqrtf(red[0] / DMODEL + 1e-5f);

    for (int d = tid; d < DMODEL; d += 256) {
        float r = (xr[d] - mu) * rstd * g[d] + b[d];
        if (yf)  yf[(size_t)row * DMODEL + d] = r;
        if (ybf) ybf[(size_t)row * DMODEL + d] = f2bf(r);
    }
}

// ---------------------------------------------------------------------------
// Transpose + f32->bf16: src [K,N] f32 -> dst [Npad,K] bf16
// ---------------------------------------------------------------------------
__global__ __launch_bounds__(256) void transp_bf16(const float* __restrict__ src,
                                                   ushort* __restrict__ dst,
                                                   int K, int N) {
    __shared__ float tile[32][33];
    const int nt = blockIdx.x * 32, kt = blockIdx.y * 32;
    const int t = threadIdx.x;
    const int lr = t >> 5, lc = t & 31;

    #pragma unroll
    for (int i = 0; i < 4; i++) {
        int k = kt + lr + i * 8, n = nt + lc;
        float v = (n < N) ? src[(size_t)k * N + n] : 0.f;
        tile[lr + i * 8][lc] = v;
    }
    __syncthreads();
    #pragma unroll
    for (int i = 0; i < 4; i++) {
        int n = nt + lr + i * 8, k = kt + lc;
        dst[(size_t)n * K + k] = f2bf(tile[lc][lr + i * 8]);
    }
}

// ---------------------------------------------------------------------------
// bf16 MFMA GEMM, 128x128 tile, BK=32, 256 thr, 4 waves.
// A [M,K] bf16, Bt [Npad,K] bf16. ACT: 0 none, 1 GELU. OUTBF: bf16 out.
// ---------------------------------------------------------------------------
template<int ACT, bool HASADD, bool OUTBF>
__global__ __launch_bounds__(256) void gemm_bf16(
    const ushort* __restrict__ A, const ushort* __restrict__ Bt,
    const float* __restrict__ bias, const float* __restrict__ addsrc,
    void* __restrict__ Cout, int N, int K)
{
    __shared__ __align__(16) ushort As[128 * 32];
    __shared__ __align__(16) ushort Bs[128 * 32];
    const int bm = blockIdx.y * 128, bn = blockIdx.x * 128;
    const int t = threadIdx.x, l = t & 63;
    const int w = t >> 6;
    const int wrb = (w >> 1) * 64, wcb = (w & 1) * 64;
    const int l15 = l & 15, lg = l >> 4;

    f32x4 acc[4][4];
    #pragma unroll
    for (int i = 0; i < 4; i++)
        #pragma unroll
        for (int j = 0; j < 4; j++) acc[i][j] = (f32x4)0.f;

    for (int k0 = 0; k0 < K; k0 += 32) {
        #pragma unroll
        for (int i = 0; i < 2; i++) {
            const int chunk = i * 256 + t;
            const int row = chunk >> 2, c8 = (chunk & 3) * 8;
            GLD16(A  + (size_t)(bm + row) * K + k0 + c8, As + chunk * 8);
            GLD16(Bt + (size_t)(bn + row) * K + k0 + c8, Bs + chunk * 8);
        }
        __syncthreads();

        short8 af[4], bfr[4];
        #pragma unroll
        for (int f = 0; f < 4; f++) {
            af[f]  = *(const short8*)(As + (wrb + f * 16 + l15) * 32 + lg * 8);
            bfr[f] = *(const short8*)(Bs + (wcb + f * 16 + l15) * 32 + lg * 8);
        }
        #pragma unroll
        for (int fm = 0; fm < 4; fm++)
            #pragma unroll
            for (int fn = 0; fn < 4; fn++)
                acc[fm][fn] = __builtin_amdgcn_mfma_f32_16x16x32_bf16(
                    af[fm], bfr[fn], acc[fm][fn], 0, 0, 0);
        __syncthreads();
    }

    #pragma unroll
    for (int fn = 0; fn < 4; fn++) {
        const int col = bn + wcb + fn * 16 + l15;
        if (col >= N) continue;
        const float bi = bias ? bias[col] : 0.f;
        #pragma unroll
        for (int fm = 0; fm < 4; fm++) {
            #pragma unroll
            for (int j = 0; j < 4; j++) {
                const int row = bm + wrb + fm * 16 + lg * 4 + j;
                float v = acc[fm][fn][j] + bi;
                if (ACT == 1) {
                    float u = 0.7978845608028654f * (v + 0.044715f * v * v * v);
                    v = 0.5f * v * (1.f + tanhf(u));
                }
                if (HASADD) v += addsrc[(size_t)row * N + col];
                if (OUTBF) ((ushort*)Cout)[(size_t)row * N + col] = f2bf(v);
                else       ((float*) Cout)[(size_t)row * N + col] = v;
            }
        }
    }
}

// ---------------------------------------------------------------------------
// Small-N GEMM: 64x128 tile, 4 waves as 2x2 (each 32x64). residual-add, f32.
// ---------------------------------------------------------------------------
__global__ __launch_bounds__(256) void gemm_bf16_s(
    const ushort* __restrict__ A, const ushort* __restrict__ Bt,
    const float* __restrict__ bias, const float* __restrict__ addsrc,
    float* __restrict__ Cout, int N, int K)
{
    __shared__ __align__(16) ushort As[64 * 32];
    __shared__ __align__(16) ushort Bs[128 * 32];
    const int bm = blockIdx.y * 64, bn = blockIdx.x * 128;
    const int t = threadIdx.x, l = t & 63;
    const int w = t >> 6;
    const int wrb = (w >> 1) * 32, wcb = (w & 1) * 64;
    const int l15 = l & 15, lg = l >> 4;

    f32x4 acc[2][4];
    #pragma unroll
    for (int i = 0; i < 2; i++)
        #pragma unroll
        for (int j = 0; j < 4; j++) acc[i][j] = (f32x4)0.f;

    for (int k0 = 0; k0 < K; k0 += 32) {
        {
            const int row = t >> 2, c8 = (t & 3) * 8;
            GLD16(A + (size_t)(bm + row) * K + k0 + c8, As + t * 8);
        }
        #pragma unroll
        for (int i = 0; i < 2; i++) {
            const int chunk = i * 256 + t;
            const int row = chunk >> 2, c8 = (chunk & 3) * 8;
            GLD16(Bt + (size_t)(bn + row) * K + k0 + c8, Bs + chunk * 8);
        }
        __syncthreads();

        short8 af[2], bfr[4];
        #pragma unroll
        for (int f = 0; f < 2; f++)
            af[f]  = *(const short8*)(As + (wrb + f * 16 + l15) * 32 + lg * 8);
        #pragma unroll
        for (int f = 0; f < 4; f++)
            bfr[f] = *(const short8*)(Bs + (wcb + f * 16 + l15) * 32 + lg * 8);
        #pragma unroll
        for (int fm = 0; fm < 2; fm++)
            #pragma unroll
            for (int fn = 0; fn < 4; fn++)
                acc[fm][fn] = __builtin_amdgcn_mfma_f32_16x16x32_bf16(
                    af[fm], bfr[fn], acc[fm][fn], 0, 0, 0);
        __syncthreads();
    }

    #pragma unroll
    for (int fn = 0; fn < 4; fn++) {
        const int col = bn + wcb + fn * 16 + l15;
        if (col >= N) continue;
        const float bi = bias ? bias[col] : 0.f;
        #pragma unroll
        for (int fm = 0; fm < 2; fm++) {
            #pragma unroll
            for (int j = 0; j < 4; j++) {
                const int row = bm + wrb + fm * 16 + lg * 4 + j;
                float v = acc[fm][fn][j] + bi + addsrc[(size_t)row * N + col];
                Cout[(size_t)row * N + col] = v;
            }
        }
    }
}

// ---------------------------------------------------------------------------
// Logits GEMM: 128x128 tile with XCD-chunked N-major/M-inner block mapping.
// Grid: 6400 1-D blocks (8 XCDs x 50 N-panels x 16 M-tiles).
// ---------------------------------------------------------------------------
__global__ __launch_bounds__(256) void gemm_logits(
    const ushort* __restrict__ A, const ushort* __restrict__ Bt,
    const float* __restrict__ bias, float* __restrict__ Cout)
{
    __shared__ __align__(16) ushort As[128 * 32];
    __shared__ __align__(16) ushort Bs[128 * 32];
    const int bid = blockIdx.x;
    const int xcd = bid & 7;
    const int slot = bid >> 3;                // 0..799 within XCD
    const int np = xcd * 50 + (slot >> 4);    // N panel
    if (np >= NVPAD / 128) return;
    const int bm = (slot & 15) * 128;
    const int bn = np * 128;
    const int t = threadIdx.x, l = t & 63;
    const int w = t >> 6;
    const int wrb = (w >> 1) * 64, wcb = (w & 1) * 64;
    const int l15 = l & 15, lg = l >> 4;

    f32x4 acc[4][4];
    #pragma unroll
    for (int i = 0; i < 4; i++)
        #pragma unroll
        for (int j = 0; j < 4; j++) acc[i][j] = (f32x4)0.f;

    for (int k0 = 0; k0 < DMODEL; k0 += 32) {
        #pragma unroll
        for (int i = 0; i < 2; i++) {
            const int chunk = i * 256 + t;
            const int row = chunk >> 2, c8 = (chunk & 3) * 8;
            GLD16(A  + (size_t)(bm + row) * DMODEL + k0 + c8, As + chunk * 8);
            GLD16(Bt + (size_t)(bn + row) * DMODEL + k0 + c8, Bs + chunk * 8);
        }
        __syncthreads();

        short8 af[4], bfr[4];
        #pragma unroll
        for (int f = 0; f < 4; f++) {
            af[f]  = *(const short8*)(As + (wrb + f * 16 + l15) * 32 + lg * 8);
            bfr[f] = *(const short8*)(Bs + (wcb + f * 16 + l15) * 32 + lg * 8);
        }
        #pragma unroll
        for (int fm = 0; fm < 4; fm++)
            #pragma unroll
            for (int fn = 0; fn < 4; fn++)
                acc[fm][fn] = __builtin_amdgcn_mfma_f32_16x16x32_bf16(
                    af[fm], bfr[fn], acc[fm][fn], 0, 0, 0);
        __syncthreads();
    }

    #pragma unroll
    for (int fn = 0; fn < 4; fn++) {
        const int col = bn + wcb + fn * 16 + l15;
        if (col >= NVOCAB) continue;
        const float bi = bias[col];
        #pragma unroll
        for (int fm = 0; fm < 4; fm++) {
            #pragma unroll
            for (int j = 0; j < 4; j++) {
                const int row = bm + wrb + fm * 16 + lg * 4 + j;
                Cout[(size_t)row * NVOCAB + col] = acc[fm][fn][j] + bi;
            }
        }
    }
}

// ---------------------------------------------------------------------------
// Build per-(head, kv-tile) swizzled K and V-transposed tile images (8 KB ea).
// Linear bytes of each image == desired (swizzled) LDS content, so attention
// stages them with pure linear global_load_lds (rule 21).
// Chunk (r, c) of K-image: K[k0+r][c*8..c*8+8); of V-image: Vt[r=d][c*8..).
// Chunk index swizzle: cidx = (r*8+c) ^ (r&7).
// ---------------------------------------------------------------------------
#define QBLK  64
#define KVBLK 64
__global__ __launch_bounds__(256) void qkv_tiles_k(const ushort* __restrict__ qkv,
                                                   ushort* __restrict__ Kimg,
                                                   ushort* __restrict__ Vimg) {
    const int h = blockIdx.x;
    const int kt = blockIdx.y;
    const int k0 = kt * KVBLK;
    const int t = threadIdx.x;
    ushort* kd = Kimg + ((size_t)h * (NCTX / KVBLK) + kt) * 4096;
    ushort* vd = Vimg + ((size_t)h * (NCTX / KVBLK) + kt) * 4096;
    #pragma unroll
    for (int i = 0; i < 2; i++) {
        int cc = t + i * 256;          // 0..511
        int r = cc >> 3, c = cc & 7;
        int cidx = (r * 8 + c) ^ (r & 7);
        // K chunk
        short8 kv8 = *(const short8*)(qkv + (size_t)(k0 + r) * D3 + DMODEL + h * HEADD + c * 8);
        *(short8*)(kd + cidx * 8) = kv8;
        // V chunk (r = d, c = kv-chunk)
        short8 vv;
        #pragma unroll
        for (int j = 0; j < 8; j++)
            vv[j] = (short)qkv[(size_t)(k0 + c * 8 + j) * D3 + 2 * DMODEL + h * HEADD + r];
        *(short8*)(vd + cidx * 8) = vv;
    }
}

// ---------------------------------------------------------------------------
// MFMA flash attention. Block = (head, 64-row q-tile), 4 waves x 16 q rows.
// K/V tiles double-buffered via linear global_load_lds from prebuilt images.
// ---------------------------------------------------------------------------
__global__ __launch_bounds__(256) void attn_mfma(const ushort* __restrict__ qkv,
                                                 const ushort* __restrict__ Kimg,
                                                 const ushort* __restrict__ Vimg,
                                                 ushort* __restrict__ o) {
    const int h  = blockIdx.x;
    const int qt = (int)(gridDim.y - 1) - (int)blockIdx.y;   // heavy tiles first
    const int q0 = qt * QBLK;
    const int t = threadIdx.x;
    const int w = t >> 6;
    const int l = t & 63;
    const int l15 = l & 15, lg = l >> 4;

    __shared__ __align__(16) ushort Ks[2][4096];
    __shared__ __align__(16) ushort Vs[2][4096];
    __shared__ __align__(16) ushort Ps[4][1024];

    const ushort* kbase = Kimg + (size_t)h * (NCTX / KVBLK) * 4096;
    const ushort* vbase = Vimg + (size_t)h * (NCTX / KVBLK) * 4096;

    // Q fragments (A layout: row=l15, k=lg*8+j), rows q0 + w*16 + l15
    const int qrow = q0 + w * 16 + l15;
    short8 qf[2];
    #pragma unroll
    for (int s = 0; s < 2; s++)
        qf[s] = *(const short8*)(qkv + (size_t)qrow * D3 + h * HEADD + s * 32 + lg * 8);

    f32x4 Of[4];
    #pragma unroll
    for (int i = 0; i < 4; i++) Of[i] = (f32x4)0.f;
    float m_run[4], l_run[4];
    #pragma unroll
    for (int j = 0; j < 4; j++) { m_run[j] = -1e30f; l_run[j] = 0.f; }

    const float scale = 0.125f;   // 1/sqrt(64)
    const int ntiles = qt + 1;

    // prologue: stage tile 0 into buffer 0
    #pragma unroll
    for (int i = 0; i < 2; i++) {
        GLD16(kbase + (size_t)(t + i * 256) * 8, &Ks[0][(t + i * 256) * 8]);
        GLD16(vbase + (size_t)(t + i * 256) * 8, &Vs[0][(t + i * 256) * 8]);
    }

    for (int kt = 0; kt < ntiles; kt++) {
        const int k0 = kt * KVBLK;
        const int cur = kt & 1;
        __syncthreads();                       // stage(kt) complete
        if (kt + 1 < ntiles) {                 // prefetch next tile
            const ushort* kim = kbase + (size_t)(kt + 1) * 4096;
            const ushort* vim = vbase + (size_t)(kt + 1) * 4096;
            #pragma unroll
            for (int i = 0; i < 2; i++) {
                GLD16(kim + (size_t)(t + i * 256) * 8, &Ks[cur ^ 1][(t + i * 256) * 8]);
                GLD16(vim + (size_t)(t + i * 256) * 8, &Vs[cur ^ 1][(t + i * 256) * 8]);
            }
        }

        // ---- S = Q @ K^T ----
        f32x4 S[4];
        #pragma unroll
        for (int nf = 0; nf < 4; nf++) {
            f32x4 a = (f32x4)0.f;
            #pragma unroll
            for (int s = 0; s < 2; s++) {
                int r = nf * 16 + l15;
                int addr = (r * 128 + s * 64 + lg * 16) ^ ((r & 7) << 4);
                short8 kf = *(const short8*)((char*)&Ks[cur][0] + addr);
                a = __builtin_amdgcn_mfma_f32_16x16x32_bf16(qf[s], kf, a, 0, 0, 0);
            }
            S[nf] = a;
        }

        // ---- mask (diagonal tile only) + online softmax ----
        float p[4][4];
        if (kt == qt) {
            #pragma unroll
            for (int nf = 0; nf < 4; nf++) {
                int kvg = k0 + nf * 16 + l15;
                #pragma unroll
                for (int j = 0; j < 4; j++) {
                    int qg = q0 + w * 16 + lg * 4 + j;
                    p[nf][j] = (kvg <= qg) ? S[nf][j] * scale : -1e30f;
                }
            }
        } else {
            #pragma unroll
            for (int nf = 0; nf < 4; nf++)
                #pragma unroll
                for (int j = 0; j < 4; j++)
                    p[nf][j] = S[nf][j] * scale;
        }
        #pragma unroll
        for (int j = 0; j < 4; j++) {
            float mx = fmaxf(fmaxf(p[0][j], p[1][j]), fmaxf(p[2][j], p[3][j]));
            mx = fmaxf(mx, __shfl_xor(mx, 1));
            mx = fmaxf(mx, __shfl_xor(mx, 2));
            mx = fmaxf(mx, __shfl_xor(mx, 4));
            mx = fmaxf(mx, __shfl_xor(mx, 8));
            float mnew = fmaxf(m_run[j], mx);
            float sc = __expf(m_run[j] - mnew);
            m_run[j] = mnew;
            float psum = 0.f;
            #pragma unroll
            for (int nf = 0; nf < 4; nf++) {
                float e = __expf(p[nf][j] - mnew);
                p[nf][j] = e;
                psum += e;
            }
            psum += __shfl_xor(psum, 1);
            psum += __shfl_xor(psum, 2);
            psum += __shfl_xor(psum, 4);
            psum += __shfl_xor(psum, 8);
            l_run[j] = l_run[j] * sc + psum;
            #pragma unroll
            for (int df = 0; df < 4; df++) Of[df][j] *= sc;
        }

        // ---- P: C-layout regs -> swizzled LDS (per wave) ----
        char* pw = (char*)&Ps[w][0];
        #pragma unroll
        for (int nf = 0; nf < 4; nf++)
            #pragma unroll
            for (int j = 0; j < 4; j++) {
                int ql = lg * 4 + j;
                int addr = (ql * 128 + (nf * 16 + l15) * 2) ^ ((ql & 7) << 4);
                *(ushort*)(pw + addr) = f2bf(p[nf][j]);
            }

        // ---- O += P @ V ----
        #pragma unroll
        for (int s = 0; s < 2; s++) {
            int paddr = (l15 * 128 + s * 64 + lg * 16) ^ ((l15 & 7) << 4);
            short8 pf = *(const short8*)(pw + paddr);
            #pragma unroll
            for (int df = 0; df < 4; df++) {
                int r = df * 16 + l15;
                int vaddr = (r * 128 + s * 64 + lg * 16) ^ ((r & 7) << 4);
                short8 vf = *(const short8*)((char*)&Vs[cur][0] + vaddr);
                Of[df] = __builtin_amdgcn_mfma_f32_16x16x32_bf16(pf, vf, Of[df], 0, 0, 0);
            }
        }
    }

    // ---- epilogue ----
    #pragma unroll
    for (int j = 0; j < 4; j++) {
        float inv = 1.f / l_run[j];
        int qg = q0 + w * 16 + lg * 4 + j;
        #pragma unroll
        for (int df = 0; df < 4; df++)
            o[(size_t)qg * DMODEL + h * HEADD + df * 16 + l15] = f2bf(Of[df][j] * inv);
    }
}

// ===========================================================================
// Fallback f32 path (only if ws too small)
// ===========================================================================
#define BM 64
#define BN 64
#define BK 16
__global__ __launch_bounds__(256)
void gemm_f32(const float* __restrict__ A, const float* __restrict__ B,
              const float* __restrict__ bias, const float* __restrict__ addsrc,
              float* __restrict__ C, int M, int N, int K, int act) {
    __shared__ float As[BK][BM];
    __shared__ float Bs[BK][BN];
    const int bm = blockIdx.y * BM;
    const int bn = blockIdx.x * BN;
    const int tid = threadIdx.x;
    const int tr = tid >> 4;
    const int tc = tid & 15;
    float acc[4][4] = {};
    for (int k0 = 0; k0 < K; k0 += BK) {
        #pragma unroll
        for (int i = 0; i < 4; i++) {
            int idx = tid + i * 256;
            int row = idx >> 4, col = idx & 15;
            int gm = bm + row;
            float v = 0.f;
            if (gm < M) v = A[(size_t)gm * K + (k0 + col)];
            As[col][row] = v;
        }
        #pragma unroll
        for (int i = 0; i < 4; i++) {
            int idx = tid + i * 256;
            int row = idx >> 6, col = idx & 63;
            int gn = bn + col;
            float v = 0.f;
            if (gn < N) v = B[(size_t)(k0 + row) * N + gn];
            Bs[row][col] = v;
        }
        __syncthreads();
        #pragma unroll
        for (int kk = 0; kk < BK; kk++) {
            float a[4], bb[4];
            #pragma unroll
            for (int i = 0; i < 4; i++) a[i] = As[kk][tr * 4 + i];
            #pragma unroll
            for (int j = 0; j < 4; j++) bb[j] = Bs[kk][tc * 4 + j];
            #pragma unroll
            for (int i = 0; i < 4; i++)
                #pragma unroll
                for (int j = 0; j < 4; j++)
                    acc[i][j] += a[i] * bb[j];
        }
        __syncthreads();
    }
    #pragma unroll
    for (int i = 0; i < 4; i++) {
        int gm = bm + tr * 4 + i;
        if (gm >= M) continue;
        #pragma unroll
        for (int j = 0; j < 4; j++) {
            int gn = bn + tc * 4 + j;
            if (gn >= N) continue;
            float v = acc[i][j] + (bias ? bias[gn] : 0.f);
            if (act == 1) {
                const float cst = 0.7978845608028654f;
                float t = tanhf(cst * (v + 0.044715f * v * v * v));
                v = 0.5f * v * (1.f + t);
            }
            if (addsrc) v += addsrc[(size_t)gm * N + gn];
            C[(size_t)gm * N + gn] = v;
        }
    }
}

__global__ __launch_bounds__(256)
void attn_k(const float* __restrict__ qkv, float* __restrict__ o) {
    const int q = blockIdx.x;
    const int h = blockIdx.y;
    const int tid = threadIdx.x;
    __shared__ float qrow[HEADD];
    __shared__ float sc[NCTX];
    __shared__ float red[256];
    __shared__ float part[4][HEADD];
    if (tid < HEADD) qrow[tid] = qkv[(size_t)q * D3 + h * HEADD + tid];
    __syncthreads();
    const float scale = 0.125f;
    float lmax = -1e30f;
    for (int k = tid; k <= q; k += 256) {
        const float* kr = qkv + (size_t)k * D3 + DMODEL + h * HEADD;
        float s = 0.f;
        #pragma unroll
        for (int d = 0; d < HEADD; d++) s += qrow[d] * kr[d];
        s *= scale;
        sc[k] = s;
        lmax = fmaxf(lmax, s);
    }
    red[tid] = lmax; __syncthreads();
    for (int off = 128; off > 0; off >>= 1) {
        if (tid < off) red[tid] = fmaxf(red[tid], red[tid + off]);
        __syncthreads();
    }
    const float m = red[0];
    __syncthreads();
    float lsum = 0.f;
    for (int k = tid; k <= q; k += 256) {
        float p = expf(sc[k] - m);
        sc[k] = p;
        lsum += p;
    }
    red[tid] = lsum; __syncthreads();
    for (int off = 128; off > 0; off >>= 1) {
        if (tid < off) red[tid] += red[tid + off];
        __syncthreads();
    }
    const float inv = 1.f / red[0];
    const int grp = tid >> 6;
    const int d = tid & 63;
    float acc = 0.f;
    for (int k = grp; k <= q; k += 4)
        acc += sc[k] * qkv[(size_t)k * D3 + 2 * DMODEL + h * HEADD + d];
    part[grp][d] = acc;
    __syncthreads();
    if (tid < HEADD) {
        float v = (part[0][tid] + part[1][tid] + part[2][tid] + part[3][tid]) * inv;
        o[(size_t)q * DMODEL + h * HEADD + tid] = v;
    }
}

// ---------------------------------------------------------------------------
// Launch
// ---------------------------------------------------------------------------
extern "C" void kernel_launch(void* const* d_in, const int* in_sizes, int n_in,
                              void* d_out, int out_size, void* d_ws, size_t ws_size,
                              hipStream_t stream) {
    const int*   tokens      = (const int*)  d_in[0];
    const float* vocab_embed = (const float*)d_in[1];
    const float* pos_embed   = (const float*)d_in[2];
    const float* ln1_g       = (const float*)d_in[3];
    const float* ln1_b       = (const float*)d_in[4];
    const float* att_w       = (const float*)d_in[5];
    const float* att_b       = (const float*)d_in[6];
    const float* attn_proj_w = (const float*)d_in[7];
    const float* attn_proj_b = (const float*)d_in[8];
    const float* ln2_g       = (const float*)d_in[9];
    const float* ln2_b       = (const float*)d_in[10];
    const float* fc_w        = (const float*)d_in[11];
    const float* fc_b        = (const float*)d_in[12];
    const float* mlp_proj_w  = (const float*)d_in[13];
    const float* mlp_proj_b  = (const float*)d_in[14];
    const float* lnf_g       = (const float*)d_in[15];
    const float* lnf_b       = (const float*)d_in[16];
    const float* out_w       = (const float*)d_in[17];
    const float* out_b       = (const float*)d_in[18];
    float* out = (float*)d_out;

    const int C = NCTX;
    dim3 blk(256);

    // ---- workspace carve for bf16 path ----
    char* wp = (char*)d_ws;
    size_t used = 0;
    auto carve = [&](size_t bytes) -> void* {
        bytes = (bytes + 255) & ~(size_t)255;
        void* p = wp + used;
        used += bytes;
        return p;
    };
    float*  x_f    = (float*) carve((size_t)C * DMODEL * 4);
    float*  h_f    = (float*) carve((size_t)C * DMODEL * 4);
    ushort* h_bf   = (ushort*)carve((size_t)C * DMODEL * 2);
    ushort* qkv_bf = (ushort*)carve((size_t)C * D3 * 2);
    ushort* o_bf   = (ushort*)carve((size_t)C * DMODEL * 2);
    ushort* mid_bf = (ushort*)carve((size_t)C * D4 * 2);
    ushort* wt_a   = (ushort*)carve((size_t)D3 * DMODEL * 2);
    ushort* wt_p   = (ushort*)carve((size_t)DMODEL * DMODEL * 2);
    ushort* wt_f   = (ushort*)carve((size_t)D4 * DMODEL * 2);
    ushort* wt_m   = (ushort*)carve((size_t)DMODEL * D4 * 2);
    ushort* wt_out = (ushort*)carve((size_t)NVPAD * DMODEL * 2);
    ushort* Kimg   = (ushort*)carve((size_t)NHEAD * (C / KVBLK) * 4096 * 2);
    ushort* Vimg   = (ushort*)carve((size_t)NHEAD * (C / KVBLK) * 4096 * 2);

    if (ws_size >= used) {
        // ================= bf16 MFMA path =================
        transp_bf16<<<dim3(NVPAD / 32, DMODEL / 32), blk, 0, stream>>>(
            out_w, wt_out, DMODEL, NVOCAB);

        embed_k<<<dim3(C), blk, 0, stream>>>(tokens, vocab_embed, pos_embed, x_f);

        for (int l = 0; l < LAYERS; l++) {
            transp_bf16<<<dim3(D3 / 32, DMODEL / 32), blk, 0, stream>>>(
                att_w + (size_t)l * DMODEL * D3, wt_a, DMODEL, D3);
            transp_bf16<<<dim3(DMODEL / 32, DMODEL / 32), blk, 0, stream>>>(
                attn_proj_w + (size_t)l * DMODEL * DMODEL, wt_p, DMODEL, DMODEL);
            transp_bf16<<<dim3(D4 / 32, DMODEL / 32), blk, 0, stream>>>(
                fc_w + (size_t)l * DMODEL * D4, wt_f, DMODEL, D4);
            transp_bf16<<<dim3(DMODEL / 32, D4 / 32), blk, 0, stream>>>(
                mlp_proj_w + (size_t)l * D4 * DMODEL, wt_m, D4, DMODEL);

            layernorm_k<<<dim3(C), blk, 0, stream>>>(
                x_f, ln1_g + l * DMODEL, ln1_b + l * DMODEL, h_f, h_bf);

            gemm_bf16<0, false, true><<<dim3(D3 / 128, C / 128), blk, 0, stream>>>(
                h_bf, wt_a, att_b + l * D3, nullptr, qkv_bf, D3, DMODEL);

            qkv_tiles_k<<<dim3(NHEAD, C / KVBLK), blk, 0, stream>>>(qkv_bf, Kimg, Vimg);

            attn_mfma<<<dim3(NHEAD, C / QBLK), blk, 0, stream>>>(qkv_bf, Kimg, Vimg, o_bf);

            gemm_bf16_s<<<dim3(DMODEL / 128, C / 64), blk, 0, stream>>>(
                o_bf, wt_p, attn_proj_b + l * DMODEL, h_f, x_f, DMODEL, DMODEL);

            layernorm_k<<<dim3(C), blk, 0, stream>>>(
                x_f, ln2_g + l * DMODEL, ln2_b + l * DMODEL, h_f, h_bf);

            gemm_bf16<1, false, true><<<dim3(D4 / 128, C / 128), blk, 0, stream>>>(
                h_bf, wt_f, fc_b + l * D4, nullptr, mid_bf, D4, DMODEL);

            gemm_bf16_s<<<dim3(DMODEL / 128, C / 64), blk, 0, stream>>>(
                mid_bf, wt_m, mlp_proj_b + l * DMODEL, h_f, x_f, DMODEL, D4);
        }

        layernorm_k<<<dim3(C), blk, 0, stream>>>(x_f, lnf_g, lnf_b, nullptr, h_bf);

        gemm_logits<<<dim3(6400), blk, 0, stream>>>(h_bf, wt_out, out_b, out);
        return;
    }

    // ================= fallback f32 path =================
    const size_t n_x   = (size_t)C * DMODEL;
    const size_t n_qkv = (size_t)C * D3;
    const size_t need_bytes = (3 * n_x + n_qkv + (size_t)C * D4) * sizeof(float);

    float *x, *h, *o, *qkv, *mid;
    float* ws = (float*)d_ws;
    if (ws_size >= need_bytes) {
        x = ws; h = x + n_x; o = h + n_x; qkv = o + n_x; mid = qkv + n_qkv;
    } else {
        x = ws; h = x + n_x; o = h + n_x;
        qkv = (float*)d_out; mid = qkv + n_qkv;
    }

    embed_k<<<dim3(C), blk, 0, stream>>>(tokens, vocab_embed, pos_embed, x);
    for (int l = 0; l < LAYERS; l++) {
        const float* lw;
        layernorm_k<<<dim3(C), blk, 0, stream>>>(x, ln1_g + l * DMODEL, ln1_b + l * DMODEL, h, nullptr);
        lw = att_w + (size_t)l * DMODEL * D3;
        gemm_f32<<<dim3(D3 / BN, C / BM), blk, 0, stream>>>(
            h, lw, att_b + l * D3, nullptr, qkv, C, D3, DMODEL, 0);
        attn_k<<<dim3(C, NHEAD), blk, 0, stream>>>(qkv, o);
        lw = attn_proj_w + (size_t)l * DMODEL * DMODEL;
        gemm_f32<<<dim3(DMODEL / BN, C / BM), blk, 0, stream>>>(
            o, lw, attn_proj_b + l * DMODEL, h, x, C, DMODEL, DMODEL, 0);
        layernorm_k<<<dim3(C), blk, 0, stream>>>(x, ln2_g + l * DMODEL, ln2_b + l * DMODEL, h, nullptr);
        lw = fc_w + (size_t)l * DMODEL * D4;
        gemm_f32<<<dim3(D4 / BN, C / BM), blk, 0, stream>>>(
            h, lw, fc_b + l * D4, nullptr, mid, C, D4, DMODEL, 1);
        lw = mlp_proj_w + (size_t)l * D4 * DMODEL;
        gemm_f32<<<dim3(DMODEL / BN, C / BM), blk, 0, stream>>>(
            mid, lw, mlp_proj_b + l * DMODEL, h, x, C, DMODEL, D4, 0);
    }
    layernorm_k<<<dim3(C), blk, 0, stream>>>(x, lnf_g, lnf_b, h, nullptr);
    gemm_f32<<<dim3((NVOCAB + BN - 1) / BN, C / BM), blk, 0, stream>>>(
        h, out_w, out_b, nullptr, out, C, NVOCAB, DMODEL, 0);
}

// Round 5
// 1255.800 us; speedup vs baseline: 9.3183x; 1.0060x over previous
//
#include <hip/hip_runtime.h>
#include <hip/hip_bf16.h>
#include <math.h>

// Problem constants
#define LAYERS 4
#define NHEAD  12
#define DMODEL 768
#define HEADD  64
#define NCTX   2048
#define NVOCAB 50257
#define NVPAD  50304            // 393*128
#define D3     (3*DMODEL)
#define D4     (4*DMODEL)

typedef short short8 __attribute__((ext_vector_type(8)));
typedef float f32x4  __attribute__((ext_vector_type(4)));
typedef float f32x4u __attribute__((ext_vector_type(4), aligned(4)));
typedef ushort ushx4 __attribute__((ext_vector_type(4)));

__device__ __forceinline__ float bf2f(ushort u) {
    union { uint i; float f; } c; c.i = ((uint)u) << 16; return c.f;
}
__device__ __forceinline__ ushort f2bf(float f) {
    union { float f; uint i; } c; c.f = f;
    uint i = c.i;
    uint r = (i + 0x7FFFu + ((i >> 16) & 1u)) >> 16;   // round-nearest-even
    return (ushort)r;
}

#define GLD16(gp, lp) __builtin_amdgcn_global_load_lds( \
    (__attribute__((address_space(1))) void*)(gp),      \
    (__attribute__((address_space(3))) void*)(lp), 16, 0, 0)

// ---------------------------------------------------------------------------
// Embedding
// ---------------------------------------------------------------------------
__global__ void embed_k(const int* __restrict__ tok,
                        const float* __restrict__ ve,
                        const float* __restrict__ pe,
                        float* __restrict__ x) {
    int c = blockIdx.x;
    int t = tok[c];
    for (int d = threadIdx.x; d < DMODEL; d += blockDim.x)
        x[(size_t)c * DMODEL + d] = ve[(size_t)t * DMODEL + d] + pe[(size_t)c * DMODEL + d];
}

// ---------------------------------------------------------------------------
// LayerNorm v2: one wave per row, single pass (sum + sumsq), shuffle-only.
// Block 256 = 4 rows. Writes f32 (optional) and bf16 (optional).
// ---------------------------------------------------------------------------
__global__ __launch_bounds__(256) void ln_v2(const float* __restrict__ x,
                                             const float* __restrict__ g,
                                             const float* __restrict__ b,
                                             float* __restrict__ yf,
                                             ushort* __restrict__ ybf) {
    const int w = threadIdx.x >> 6, l = threadIdx.x & 63;
    const int row = blockIdx.x * 4 + w;
    const float* xr = x + (size_t)row * DMODEL;

    f32x4 v[3];
    float s = 0.f, ss = 0.f;
    #pragma unroll
    for (int i = 0; i < 3; i++) {
        v[i] = *(const f32x4*)(xr + (l + 64 * i) * 4);
        #pragma unroll
        for (int k = 0; k < 4; k++) { s += v[i][k]; ss += v[i][k] * v[i][k]; }
    }
    #pragma unroll
    for (int off = 32; off > 0; off >>= 1) {
        s  += __shfl_xor(s, off);
        ss += __shfl_xor(ss, off);
    }
    const float mu = s * (1.f / DMODEL);
    const float var = ss * (1.f / DMODEL) - mu * mu;
    const float rstd = rsqrtf(var + 1e-5f);

    #pragma unroll
    for (int i = 0; i < 3; i++) {
        const int idx = l + 64 * i;
        f32x4 g4 = *(const f32x4*)(g + idx * 4);
        f32x4 b4 = *(const f32x4*)(b + idx * 4);
        f32x4 r;
        #pragma unroll
        for (int k = 0; k < 4; k++) r[k] = (v[i][k] - mu) * rstd * g4[k] + b4[k];
        if (yf) *(f32x4*)(yf + (size_t)row * DMODEL + idx * 4) = r;
        if (ybf) {
            ushx4 u;
            #pragma unroll
            for (int k = 0; k < 4; k++) u[k] = f2bf(r[k]);
            *(ushx4*)(ybf + (size_t)row * DMODEL + idx * 4) = u;
        }
    }
}

// ---------------------------------------------------------------------------
// Transpose + f32->bf16: src [K,N] f32 -> dst [Npad,K] bf16
// ---------------------------------------------------------------------------
__global__ __launch_bounds__(256) void transp_bf16(const float* __restrict__ src,
                                                   ushort* __restrict__ dst,
                                                   int K, int N) {
    __shared__ float tile[32][33];
    const int nt = blockIdx.x * 32, kt = blockIdx.y * 32;
    const int t = threadIdx.x;
    const int lr = t >> 5, lc = t & 31;

    #pragma unroll
    for (int i = 0; i < 4; i++) {
        int k = kt + lr + i * 8, n = nt + lc;
        float v = (n < N) ? src[(size_t)k * N + n] : 0.f;
        tile[lr + i * 8][lc] = v;
    }
    __syncthreads();
    #pragma unroll
    for (int i = 0; i < 4; i++) {
        int n = nt + lr + i * 8, k = kt + lc;
        dst[(size_t)n * K + k] = f2bf(tile[lc][lr + i * 8]);
    }
}

// ===========================================================================
// BK=64 swizzled staging helpers.
// LDS tile layout: row stride 128 B (64 bf16), phys_byte = logical ^ ((row&7)<<4).
// Stage: linear LDS dest chunk c (16 B); source k-chunk = (c&7)^(row&7).
// Frag read (row, s, lg): byte = (row*128 + s*64 + lg*16) ^ ((row&7)<<4).
// ===========================================================================

// ---------------------------------------------------------------------------
// bf16 MFMA GEMM, 128x128 tile, BK=64, 256 thr, 4 waves, T2 swizzle.
// A [M,K] bf16, Bt [Npad,K] bf16. ACT: 0 none, 1 GELU. OUTBF: bf16 out.
// ---------------------------------------------------------------------------
template<int ACT, bool HASADD, bool OUTBF>
__global__ __launch_bounds__(256) void gemm_bf16(
    const ushort* __restrict__ A, const ushort* __restrict__ Bt,
    const float* __restrict__ bias, const float* __restrict__ addsrc,
    void* __restrict__ Cout, int N, int K)
{
    __shared__ __align__(16) ushort As[128 * 64];
    __shared__ __align__(16) ushort Bs[128 * 64];
    const int bm = blockIdx.y * 128, bn = blockIdx.x * 128;
    const int t = threadIdx.x, l = t & 63;
    const int w = t >> 6;
    const int wrb = (w >> 1) * 64, wcb = (w & 1) * 64;
    const int l15 = l & 15, lg = l >> 4;
    const int sw = (l15 & 7) << 4;

    f32x4 acc[4][4];
    #pragma unroll
    for (int i = 0; i < 4; i++)
        #pragma unroll
        for (int j = 0; j < 4; j++) acc[i][j] = (f32x4)0.f;

    for (int k0 = 0; k0 < K; k0 += 64) {
        #pragma unroll
        for (int i = 0; i < 4; i++) {
            const int c = i * 256 + t;
            const int row = c >> 3;
            const int sc = ((c & 7) ^ (row & 7)) * 8;
            GLD16(A  + (size_t)(bm + row) * K + k0 + sc, As + c * 8);
            GLD16(Bt + (size_t)(bn + row) * K + k0 + sc, Bs + c * 8);
        }
        __syncthreads();

        #pragma unroll
        for (int s = 0; s < 2; s++) {
            short8 af[4], bfr[4];
            #pragma unroll
            for (int f = 0; f < 4; f++) {
                af[f]  = *(const short8*)((const char*)As +
                         (((wrb + f * 16 + l15) * 128 + s * 64 + lg * 16) ^ sw));
                bfr[f] = *(const short8*)((const char*)Bs +
                         (((wcb + f * 16 + l15) * 128 + s * 64 + lg * 16) ^ sw));
            }
            #pragma unroll
            for (int fm = 0; fm < 4; fm++)
                #pragma unroll
                for (int fn = 0; fn < 4; fn++)
                    acc[fm][fn] = __builtin_amdgcn_mfma_f32_16x16x32_bf16(
                        af[fm], bfr[fn], acc[fm][fn], 0, 0, 0);
        }
        __syncthreads();
    }

    #pragma unroll
    for (int fn = 0; fn < 4; fn++) {
        const int col = bn + wcb + fn * 16 + l15;
        if (col >= N) continue;
        const float bi = bias ? bias[col] : 0.f;
        #pragma unroll
        for (int fm = 0; fm < 4; fm++) {
            #pragma unroll
            for (int j = 0; j < 4; j++) {
                const int row = bm + wrb + fm * 16 + lg * 4 + j;
                float v = acc[fm][fn][j] + bi;
                if (ACT == 1) {
                    float u = 0.7978845608028654f * (v + 0.044715f * v * v * v);
                    v = 0.5f * v * (1.f + tanhf(u));
                }
                if (HASADD) v += addsrc[(size_t)row * N + col];
                if (OUTBF) ((ushort*)Cout)[(size_t)row * N + col] = f2bf(v);
                else       ((float*) Cout)[(size_t)row * N + col] = v;
            }
        }
    }
}

// ---------------------------------------------------------------------------
// Small-M GEMM: 64x128 tile, BK=64, swizzled. residual-add, f32 out.
// ---------------------------------------------------------------------------
__global__ __launch_bounds__(256) void gemm_bf16_s(
    const ushort* __restrict__ A, const ushort* __restrict__ Bt,
    const float* __restrict__ bias, const float* __restrict__ addsrc,
    float* __restrict__ Cout, int N, int K)
{
    __shared__ __align__(16) ushort As[64 * 64];
    __shared__ __align__(16) ushort Bs[128 * 64];
    const int bm = blockIdx.y * 64, bn = blockIdx.x * 128;
    const int t = threadIdx.x, l = t & 63;
    const int w = t >> 6;
    const int wrb = (w >> 1) * 32, wcb = (w & 1) * 64;
    const int l15 = l & 15, lg = l >> 4;
    const int sw = (l15 & 7) << 4;

    f32x4 acc[2][4];
    #pragma unroll
    for (int i = 0; i < 2; i++)
        #pragma unroll
        for (int j = 0; j < 4; j++) acc[i][j] = (f32x4)0.f;

    for (int k0 = 0; k0 < K; k0 += 64) {
        #pragma unroll
        for (int i = 0; i < 2; i++) {
            const int c = i * 256 + t;
            const int row = c >> 3;
            const int sc = ((c & 7) ^ (row & 7)) * 8;
            GLD16(A + (size_t)(bm + row) * K + k0 + sc, As + c * 8);
        }
        #pragma unroll
        for (int i = 0; i < 4; i++) {
            const int c = i * 256 + t;
            const int row = c >> 3;
            const int sc = ((c & 7) ^ (row & 7)) * 8;
            GLD16(Bt + (size_t)(bn + row) * K + k0 + sc, Bs + c * 8);
        }
        __syncthreads();

        #pragma unroll
        for (int s = 0; s < 2; s++) {
            short8 af[2], bfr[4];
            #pragma unroll
            for (int f = 0; f < 2; f++)
                af[f] = *(const short8*)((const char*)As +
                        (((wrb + f * 16 + l15) * 128 + s * 64 + lg * 16) ^ sw));
            #pragma unroll
            for (int f = 0; f < 4; f++)
                bfr[f] = *(const short8*)((const char*)Bs +
                         (((wcb + f * 16 + l15) * 128 + s * 64 + lg * 16) ^ sw));
            #pragma unroll
            for (int fm = 0; fm < 2; fm++)
                #pragma unroll
                for (int fn = 0; fn < 4; fn++)
                    acc[fm][fn] = __builtin_amdgcn_mfma_f32_16x16x32_bf16(
                        af[fm], bfr[fn], acc[fm][fn], 0, 0, 0);
        }
        __syncthreads();
    }

    #pragma unroll
    for (int fn = 0; fn < 4; fn++) {
        const int col = bn + wcb + fn * 16 + l15;
        if (col >= N) continue;
        const float bi = bias ? bias[col] : 0.f;
        #pragma unroll
        for (int fm = 0; fm < 2; fm++) {
            #pragma unroll
            for (int j = 0; j < 4; j++) {
                const int row = bm + wrb + fm * 16 + lg * 4 + j;
                Cout[(size_t)row * N + col] = acc[fm][fn][j] + bi + addsrc[(size_t)row * N + col];
            }
        }
    }
}

// ---------------------------------------------------------------------------
// Logits GEMM: 128x128, BK=64 swizzled, XCD-chunked mapping, LDS-staged
// coalesced f32 epilogue. Grid: 6400 1-D blocks.
// ---------------------------------------------------------------------------
__global__ __launch_bounds__(256) void gemm_logits(
    const ushort* __restrict__ A, const ushort* __restrict__ Bt,
    const float* __restrict__ bias, float* __restrict__ Cout)
{
    __shared__ __align__(16) char smem[32768];
    ushort* As = (ushort*)smem;
    ushort* Bs = (ushort*)(smem + 16384);
    float*  Cs = (float*)smem;

    const int bid = blockIdx.x;
    const int xcd = bid & 7;
    const int slot = bid >> 3;
    const int np = xcd * 50 + (slot >> 4);
    if (np >= NVPAD / 128) return;
    const int bm = (slot & 15) * 128;
    const int bn = np * 128;
    const int t = threadIdx.x, l = t & 63;
    const int w = t >> 6;
    const int wrb = (w >> 1) * 64, wcb = (w & 1) * 64;
    const int l15 = l & 15, lg = l >> 4;
    const int sw = (l15 & 7) << 4;

    f32x4 acc[4][4];
    #pragma unroll
    for (int i = 0; i < 4; i++)
        #pragma unroll
        for (int j = 0; j < 4; j++) acc[i][j] = (f32x4)0.f;

    for (int k0 = 0; k0 < DMODEL; k0 += 64) {
        #pragma unroll
        for (int i = 0; i < 4; i++) {
            const int c = i * 256 + t;
            const int row = c >> 3;
            const int sc = ((c & 7) ^ (row & 7)) * 8;
            GLD16(A  + (size_t)(bm + row) * DMODEL + k0 + sc, As + c * 8);
            GLD16(Bt + (size_t)(bn + row) * DMODEL + k0 + sc, Bs + c * 8);
        }
        __syncthreads();

        #pragma unroll
        for (int s = 0; s < 2; s++) {
            short8 af[4], bfr[4];
            #pragma unroll
            for (int f = 0; f < 4; f++) {
                af[f]  = *(const short8*)((const char*)As +
                         (((wrb + f * 16 + l15) * 128 + s * 64 + lg * 16) ^ sw));
                bfr[f] = *(const short8*)((const char*)Bs +
                         (((wcb + f * 16 + l15) * 128 + s * 64 + lg * 16) ^ sw));
            }
            #pragma unroll
            for (int fm = 0; fm < 4; fm++)
                #pragma unroll
                for (int fn = 0; fn < 4; fn++)
                    acc[fm][fn] = __builtin_amdgcn_mfma_f32_16x16x32_bf16(
                        af[fm], bfr[fn], acc[fm][fn], 0, 0, 0);
        }
        __syncthreads();
    }

    // LDS-staged epilogue: two 64-row halves through 32 KB Cs, coalesced writes.
    #pragma unroll
    for (int half = 0; half < 2; half++) {
        __syncthreads();
        if ((w >> 1) == half) {
            #pragma unroll
            for (int fn = 0; fn < 4; fn++) {
                const int col = bn + wcb + fn * 16 + l15;
                const float bi = (col < NVOCAB) ? bias[col] : 0.f;
                #pragma unroll
                for (int fm = 0; fm < 4; fm++)
                    #pragma unroll
                    for (int j = 0; j < 4; j++)
                        Cs[(fm * 16 + lg * 4 + j) * 128 + wcb + fn * 16 + l15] =
                            acc[fm][fn][j] + bi;
            }
        }
        __syncthreads();
        const int grow0 = bm + half * 64;
        #pragma unroll
        for (int i = 0; i < 2; i++) {
            const int idx = t + i * 256;
            const int r = idx >> 3, ch = idx & 7;
            const float* src = Cs + r * 128 + ch * 16;
            float* dst = Cout + (size_t)(grow0 + r) * NVOCAB + bn + ch * 16;
            if (bn + 128 <= NVOCAB) {
                #pragma unroll
                for (int k = 0; k < 4; k++)
                    *(f32x4u*)(dst + k * 4) = *(const f32x4*)(src + k * 4);
            } else {
                #pragma unroll
                for (int k = 0; k < 16; k++)
                    if (bn + ch * 16 + k < NVOCAB) dst[k] = src[k];
            }
        }
    }
}

// ---------------------------------------------------------------------------
// Build per-(head, kv-tile) swizzled K and V^T tile images (8 KB each).
// Linear image bytes == swizzled LDS content (rule 21).
// K: chunk permutation, coalesced. V: coalesced row reads -> LDS transpose
// scatter -> linear copy out.
// ---------------------------------------------------------------------------
#define QBLK  64
#define KVBLK 64
__global__ __launch_bounds__(256) void qkv_tiles_k(const ushort* __restrict__ qkv,
                                                   ushort* __restrict__ Kimg,
                                                   ushort* __restrict__ Vimg) {
    __shared__ __align__(16) ushort Vt_l[4096];
    const int h = blockIdx.x;
    const int kt = blockIdx.y;
    const int k0 = kt * KVBLK;
    const int t = threadIdx.x;
    ushort* kd = Kimg + ((size_t)h * (NCTX / KVBLK) + kt) * 4096;
    ushort* vd = Vimg + ((size_t)h * (NCTX / KVBLK) + kt) * 4096;

    #pragma unroll
    for (int i = 0; i < 2; i++) {
        const int c = t + i * 256;          // 0..511
        const int r = c >> 3, cc = c & 7;
        // K image: chunk permute (coalesced read, 16B scatter within 8KB)
        short8 kv8 = *(const short8*)(qkv + (size_t)(k0 + r) * D3 + DMODEL + h * HEADD + cc * 8);
        *(short8*)(kd + (((r * 8 + cc) ^ (r & 7)) * 8)) = kv8;
        // V: coalesced row read, transpose-scatter into LDS (swizzled)
        short8 vv = *(const short8*)(qkv + (size_t)(k0 + r) * D3 + 2 * DMODEL + h * HEADD + cc * 8);
        #pragma unroll
        for (int j = 0; j < 8; j++) {
            const int d = cc * 8 + j;
            const int addr = (d * 128 + r * 2) ^ ((d & 7) << 4);
            *(ushort*)((char*)Vt_l + addr) = (ushort)vv[j];
        }
    }
    __syncthreads();
    #pragma unroll
    for (int i = 0; i < 2; i++) {
        const int c = t + i * 256;
        *(short8*)(vd + c * 8) = *(const short8*)(Vt_l + c * 8);
    }
}

// ---------------------------------------------------------------------------
// One attention stream step: S = Q K^T, online softmax, O += P V.
// All state in registers (static indexing); per-wave Ps LDS round-trip.
// ---------------------------------------------------------------------------
__device__ __forceinline__ void attn_step(
    const short8 qf[2], f32x4 Of[4], float m_run[4], float l_run[4],
    const ushort* Kt, const ushort* Vt, char* pw,
    int k0, int q0, int maskTile, int w, int l15, int lg)
{
    const float scale = 0.125f;
    f32x4 S[4];
    #pragma unroll
    for (int nf = 0; nf < 4; nf++) {
        f32x4 a = (f32x4)0.f;
        #pragma unroll
        for (int s = 0; s < 2; s++) {
            const int r = nf * 16 + l15;
            const int addr = (r * 128 + s * 64 + lg * 16) ^ ((r & 7) << 4);
            short8 kf = *(const short8*)((const char*)Kt + addr);
            a = __builtin_amdgcn_mfma_f32_16x16x32_bf16(qf[s], kf, a, 0, 0, 0);
        }
        S[nf] = a;
    }

    float p[4][4];
    if (maskTile) {
        #pragma unroll
        for (int nf = 0; nf < 4; nf++) {
            const int kvg = k0 + nf * 16 + l15;
            #pragma unroll
            for (int j = 0; j < 4; j++) {
                const int qg = q0 + w * 16 + lg * 4 + j;
                p[nf][j] = (kvg <= qg) ? S[nf][j] * scale : -1e30f;
            }
        }
    } else {
        #pragma unroll
        for (int nf = 0; nf < 4; nf++)
            #pragma unroll
            for (int j = 0; j < 4; j++)
                p[nf][j] = S[nf][j] * scale;
    }

    #pragma unroll
    for (int j = 0; j < 4; j++) {
        float mx = fmaxf(fmaxf(p[0][j], p[1][j]), fmaxf(p[2][j], p[3][j]));
        mx = fmaxf(mx, __shfl_xor(mx, 1));
        mx = fmaxf(mx, __shfl_xor(mx, 2));
        mx = fmaxf(mx, __shfl_xor(mx, 4));
        mx = fmaxf(mx, __shfl_xor(mx, 8));
        const float mnew = fmaxf(m_run[j], mx);
        const float sc = __expf(m_run[j] - mnew);
        m_run[j] = mnew;
        float psum = 0.f;
        #pragma unroll
        for (int nf = 0; nf < 4; nf++) {
            const float e = __expf(p[nf][j] - mnew);
            p[nf][j] = e;
            psum += e;
        }
        psum += __shfl_xor(psum, 1);
        psum += __shfl_xor(psum, 2);
        psum += __shfl_xor(psum, 4);
        psum += __shfl_xor(psum, 8);
        l_run[j] = l_run[j] * sc + psum;
        #pragma unroll
        for (int df = 0; df < 4; df++) Of[df][j] *= sc;
    }

    // P: C-layout regs -> swizzled per-wave LDS
    #pragma unroll
    for (int nf = 0; nf < 4; nf++)
        #pragma unroll
        for (int j = 0; j < 4; j++) {
            const int ql = lg * 4 + j;
            const int addr = (ql * 128 + (nf * 16 + l15) * 2) ^ ((ql & 7) << 4);
            *(ushort*)(pw + addr) = f2bf(p[nf][j]);
        }

    // O += P @ V
    #pragma unroll
    for (int s = 0; s < 2; s++) {
        const int paddr = (l15 * 128 + s * 64 + lg * 16) ^ ((l15 & 7) << 4);
        short8 pf = *(const short8*)(pw + paddr);
        #pragma unroll
        for (int df = 0; df < 4; df++) {
            const int r = df * 16 + l15;
            const int vaddr = (r * 128 + s * 64 + lg * 16) ^ ((r & 7) << 4);
            short8 vf = *(const short8*)((const char*)Vt + vaddr);
            Of[df] = __builtin_amdgcn_mfma_f32_16x16x32_bf16(pf, vf, Of[df], 0, 0, 0);
        }
    }
}

// ---------------------------------------------------------------------------
// MFMA flash attention with tile pairing: block = (head, pair), pair p handles
// q-tiles (p, 31-p). 192 equal-work blocks; each KV tile staged once for both.
// ---------------------------------------------------------------------------
__global__ __launch_bounds__(256) void attn_mfma2(const ushort* __restrict__ qkv,
                                                  const ushort* __restrict__ Kimg,
                                                  const ushort* __restrict__ Vimg,
                                                  ushort* __restrict__ o) {
    const int h   = blockIdx.x;
    const int qaT = blockIdx.y;          // 0..15
    const int qbT = 31 - qaT;            // 16..31
    const int q0a = qaT * QBLK, q0b = qbT * QBLK;
    const int t = threadIdx.x;
    const int w = t >> 6;
    const int l = t & 63;
    const int l15 = l & 15, lg = l >> 4;

    __shared__ __align__(16) ushort Ks[2][4096];
    __shared__ __align__(16) ushort Vs[2][4096];
    __shared__ __align__(16) ushort Ps[4][1024];

    const ushort* kbase = Kimg + (size_t)h * (NCTX / KVBLK) * 4096;
    const ushort* vbase = Vimg + (size_t)h * (NCTX / KVBLK) * 4096;
    char* pw = (char*)&Ps[w][0];

    short8 qfa[2], qfb[2];
    {
        const int qra = q0a + w * 16 + l15;
        const int qrb = q0b + w * 16 + l15;
        #pragma unroll
        for (int s = 0; s < 2; s++) {
            qfa[s] = *(const short8*)(qkv + (size_t)qra * D3 + h * HEADD + s * 32 + lg * 8);
            qfb[s] = *(const short8*)(qkv + (size_t)qrb * D3 + h * HEADD + s * 32 + lg * 8);
        }
    }

    f32x4 OfA[4], OfB[4];
    float mA[4], lA[4], mB[4], lB[4];
    #pragma unroll
    for (int i = 0; i < 4; i++) {
        OfA[i] = (f32x4)0.f; OfB[i] = (f32x4)0.f;
        mA[i] = -1e30f; lA[i] = 0.f; mB[i] = -1e30f; lB[i] = 0.f;
    }

    const int ntiles = qbT + 1;

    // prologue: stage tile 0
    #pragma unroll
    for (int i = 0; i < 2; i++) {
        GLD16(kbase + (size_t)(t + i * 256) * 8, &Ks[0][(t + i * 256) * 8]);
        GLD16(vbase + (size_t)(t + i * 256) * 8, &Vs[0][(t + i * 256) * 8]);
    }

    for (int kt = 0; kt < ntiles; kt++) {
        const int k0 = kt * KVBLK;
        const int cur = kt & 1;
        __syncthreads();
        if (kt + 1 < ntiles) {
            const ushort* kim = kbase + (size_t)(kt + 1) * 4096;
            const ushort* vim = vbase + (size_t)(kt + 1) * 4096;
            #pragma unroll
            for (int i = 0; i < 2; i++) {
                GLD16(kim + (size_t)(t + i * 256) * 8, &Ks[cur ^ 1][(t + i * 256) * 8]);
                GLD16(vim + (size_t)(t + i * 256) * 8, &Vs[cur ^ 1][(t + i * 256) * 8]);
            }
        }

        // stream B (always active; kt ranges 0..qbT)
        attn_step(qfb, OfB, mB, lB, &Ks[cur][0], &Vs[cur][0], pw,
                  k0, q0b, (kt == qbT) ? 1 : 0, w, l15, lg);
        // stream A (active while kt <= qaT)
        if (kt <= qaT)
            attn_step(qfa, OfA, mA, lA, &Ks[cur][0], &Vs[cur][0], pw,
                      k0, q0a, (kt == qaT) ? 1 : 0, w, l15, lg);
    }

    #pragma unroll
    for (int j = 0; j < 4; j++) {
        const float invA = 1.f / lA[j];
        const float invB = 1.f / lB[j];
        const int qga = q0a + w * 16 + lg * 4 + j;
        const int qgb = q0b + w * 16 + lg * 4 + j;
        #pragma unroll
        for (int df = 0; df < 4; df++) {
            o[(size_t)qga * DMODEL + h * HEADD + df * 16 + l15] = f2bf(OfA[df][j] * invA);
            o[(size_t)qgb * DMODEL + h * HEADD + df * 16 + l15] = f2bf(OfB[df][j] * invB);
        }
    }
}

// ===========================================================================
// Fallback f32 path (only if ws too small)
// ===========================================================================
__global__ void layernorm_k(const float* __restrict__ x,
                            const float* __restrict__ g,
                            const float* __restrict__ b,
                            float* __restrict__ y) {
    const int row = blockIdx.x;
    const float* xr = x + (size_t)row * DMODEL;
    __shared__ float red[256];
    const int tid = threadIdx.x;
    float s = 0.f;
    for (int d = tid; d < DMODEL; d += 256) s += xr[d];
    red[tid] = s; __syncthreads();
    for (int off = 128; off > 0; off >>= 1) {
        if (tid < off) red[tid] += red[tid + off];
        __syncthreads();
    }
    const float mu = red[0] / DMODEL;
    __syncthreads();
    float v = 0.f;
    for (int d = tid; d < DMODEL; d += 256) { float tv = xr[d] - mu; v += tv * tv; }
    red[tid] = v; __syncthreads();
    for (int off = 128; off > 0; off >>= 1) {
        if (tid < off) red[tid] += red[tid + off];
        __syncthreads();
    }
    const float rstd = rsqrtf(red[0] / DMODEL + 1e-5f);
    for (int d = tid; d < DMODEL; d += 256)
        y[(size_t)row * DMODEL + d] = (xr[d] - mu) * rstd * g[d] + b[d];
}

#define BM 64
#define BN 64
#define BK 16
__global__ __launch_bounds__(256)
void gemm_f32(const float* __restrict__ A, const float* __restrict__ B,
              const float* __restrict__ bias, const float* __restrict__ addsrc,
              float* __restrict__ C, int M, int N, int K, int act) {
    __shared__ float As[BK][BM];
    __shared__ float Bs[BK][BN];
    const int bm = blockIdx.y * BM;
    const int bn = blockIdx.x * BN;
    const int tid = threadIdx.x;
    const int tr = tid >> 4;
    const int tc = tid & 15;
    float acc[4][4] = {};
    for (int k0 = 0; k0 < K; k0 += BK) {
        #pragma unroll
        for (int i = 0; i < 4; i++) {
            int idx = tid + i * 256;
            int row = idx >> 4, col = idx & 15;
            int gm = bm + row;
            float v = 0.f;
            if (gm < M) v = A[(size_t)gm * K + (k0 + col)];
            As[col][row] = v;
        }
        #pragma unroll
        for (int i = 0; i < 4; i++) {
            int idx = tid + i * 256;
            int row = idx >> 6, col = idx & 63;
            int gn = bn + col;
            float v = 0.f;
            if (gn < N) v = B[(size_t)(k0 + row) * N + gn];
            Bs[row][col] = v;
        }
        __syncthreads();
        #pragma unroll
        for (int kk = 0; kk < BK; kk++) {
            float a[4], bb[4];
            #pragma unroll
            for (int i = 0; i < 4; i++) a[i] = As[kk][tr * 4 + i];
            #pragma unroll
            for (int j = 0; j < 4; j++) bb[j] = Bs[kk][tc * 4 + j];
            #pragma unroll
            for (int i = 0; i < 4; i++)
                #pragma unroll
                for (int j = 0; j < 4; j++)
                    acc[i][j] += a[i] * bb[j];
        }
        __syncthreads();
    }
    #pragma unroll
    for (int i = 0; i < 4; i++) {
        int gm = bm + tr * 4 + i;
        if (gm >= M) continue;
        #pragma unroll
        for (int j = 0; j < 4; j++) {
            int gn = bn + tc * 4 + j;
            if (gn >= N) continue;
            float v = acc[i][j] + (bias ? bias[gn] : 0.f);
            if (act == 1) {
                const float cst = 0.7978845608028654f;
                float tt = tanhf(cst * (v + 0.044715f * v * v * v));
                v = 0.5f * v * (1.f + tt);
            }
            if (addsrc) v += addsrc[(size_t)gm * N + gn];
            C[(size_t)gm * N + gn] = v;
        }
    }
}

__global__ __launch_bounds__(256)
void attn_k(const float* __restrict__ qkv, float* __restrict__ o) {
    const int q = blockIdx.x;
    const int h = blockIdx.y;
    const int tid = threadIdx.x;
    __shared__ float qrow[HEADD];
    __shared__ float sc[NCTX];
    __shared__ float red[256];
    __shared__ float part[4][HEADD];
    if (tid < HEADD) qrow[tid] = qkv[(size_t)q * D3 + h * HEADD + tid];
    __syncthreads();
    const float scale = 0.125f;
    float lmax = -1e30f;
    for (int k = tid; k <= q; k += 256) {
        const float* kr = qkv + (size_t)k * D3 + DMODEL + h * HEADD;
        float s = 0.f;
        #pragma unroll
        for (int d = 0; d < HEADD; d++) s += qrow[d] * kr[d];
        s *= scale;
        sc[k] = s;
        lmax = fmaxf(lmax, s);
    }
    red[tid] = lmax; __syncthreads();
    for (int off = 128; off > 0; off >>= 1) {
        if (tid < off) red[tid] = fmaxf(red[tid], red[tid + off]);
        __syncthreads();
    }
    const float m = red[0];
    __syncthreads();
    float lsum = 0.f;
    for (int k = tid; k <= q; k += 256) {
        float p = expf(sc[k] - m);
        sc[k] = p;
        lsum += p;
    }
    red[tid] = lsum; __syncthreads();
    for (int off = 128; off > 0; off >>= 1) {
        if (tid < off) red[tid] += red[tid + off];
        __syncthreads();
    }
    const float inv = 1.f / red[0];
    const int grp = tid >> 6;
    const int d = tid & 63;
    float acc = 0.f;
    for (int k = grp; k <= q; k += 4)
        acc += sc[k] * qkv[(size_t)k * D3 + 2 * DMODEL + h * HEADD + d];
    part[grp][d] = acc;
    __syncthreads();
    if (tid < HEADD) {
        float v = (part[0][tid] + part[1][tid] + part[2][tid] + part[3][tid]) * inv;
        o[(size_t)q * DMODEL + h * HEADD + tid] = v;
    }
}

// ---------------------------------------------------------------------------
// Launch
// ---------------------------------------------------------------------------
extern "C" void kernel_launch(void* const* d_in, const int* in_sizes, int n_in,
                              void* d_out, int out_size, void* d_ws, size_t ws_size,
                              hipStream_t stream) {
    const int*   tokens      = (const int*)  d_in[0];
    const float* vocab_embed = (const float*)d_in[1];
    const float* pos_embed   = (const float*)d_in[2];
    const float* ln1_g       = (const float*)d_in[3];
    const float* ln1_b       = (const float*)d_in[4];
    const float* att_w       = (const float*)d_in[5];
    const float* att_b       = (const float*)d_in[6];
    const float* attn_proj_w = (const float*)d_in[7];
    const float* attn_proj_b = (const float*)d_in[8];
    const float* ln2_g       = (const float*)d_in[9];
    const float* ln2_b       = (const float*)d_in[10];
    const float* fc_w        = (const float*)d_in[11];
    const float* fc_b        = (const float*)d_in[12];
    const float* mlp_proj_w  = (const float*)d_in[13];
    const float* mlp_proj_b  = (const float*)d_in[14];
    const float* lnf_g       = (const float*)d_in[15];
    const float* lnf_b       = (const float*)d_in[16];
    const float* out_w       = (const float*)d_in[17];
    const float* out_b       = (const float*)d_in[18];
    float* out = (float*)d_out;

    const int C = NCTX;
    dim3 blk(256);

    // ---- workspace carve for bf16 path ----
    char* wp = (char*)d_ws;
    size_t used = 0;
    auto carve = [&](size_t bytes) -> void* {
        bytes = (bytes + 255) & ~(size_t)255;
        void* p = wp + used;
        used += bytes;
        return p;
    };
    float*  x_f    = (float*) carve((size_t)C * DMODEL * 4);
    float*  h_f    = (float*) carve((size_t)C * DMODEL * 4);
    ushort* h_bf   = (ushort*)carve((size_t)C * DMODEL * 2);
    ushort* qkv_bf = (ushort*)carve((size_t)C * D3 * 2);
    ushort* o_bf   = (ushort*)carve((size_t)C * DMODEL * 2);
    ushort* mid_bf = (ushort*)carve((size_t)C * D4 * 2);
    ushort* wt_a   = (ushort*)carve((size_t)D3 * DMODEL * 2);
    ushort* wt_p   = (ushort*)carve((size_t)DMODEL * DMODEL * 2);
    ushort* wt_f   = (ushort*)carve((size_t)D4 * DMODEL * 2);
    ushort* wt_m   = (ushort*)carve((size_t)DMODEL * D4 * 2);
    ushort* wt_out = (ushort*)carve((size_t)NVPAD * DMODEL * 2);
    ushort* Kimg   = (ushort*)carve((size_t)NHEAD * (C / KVBLK) * 4096 * 2);
    ushort* Vimg   = (ushort*)carve((size_t)NHEAD * (C / KVBLK) * 4096 * 2);

    if (ws_size >= used) {
        // ================= bf16 MFMA path =================
        transp_bf16<<<dim3(NVPAD / 32, DMODEL / 32), blk, 0, stream>>>(
            out_w, wt_out, DMODEL, NVOCAB);

        embed_k<<<dim3(C), blk, 0, stream>>>(tokens, vocab_embed, pos_embed, x_f);

        for (int l = 0; l < LAYERS; l++) {
            transp_bf16<<<dim3(D3 / 32, DMODEL / 32), blk, 0, stream>>>(
                att_w + (size_t)l * DMODEL * D3, wt_a, DMODEL, D3);
            transp_bf16<<<dim3(DMODEL / 32, DMODEL / 32), blk, 0, stream>>>(
                attn_proj_w + (size_t)l * DMODEL * DMODEL, wt_p, DMODEL, DMODEL);
            transp_bf16<<<dim3(D4 / 32, DMODEL / 32), blk, 0, stream>>>(
                fc_w + (size_t)l * DMODEL * D4, wt_f, DMODEL, D4);
            transp_bf16<<<dim3(DMODEL / 32, D4 / 32), blk, 0, stream>>>(
                mlp_proj_w + (size_t)l * D4 * DMODEL, wt_m, D4, DMODEL);

            ln_v2<<<dim3(C / 4), blk, 0, stream>>>(
                x_f, ln1_g + l * DMODEL, ln1_b + l * DMODEL, h_f, h_bf);

            gemm_bf16<0, false, true><<<dim3(D3 / 128, C / 128), blk, 0, stream>>>(
                h_bf, wt_a, att_b + l * D3, nullptr, qkv_bf, D3, DMODEL);

            qkv_tiles_k<<<dim3(NHEAD, C / KVBLK), blk, 0, stream>>>(qkv_bf, Kimg, Vimg);

            attn_mfma2<<<dim3(NHEAD, 16), blk, 0, stream>>>(qkv_bf, Kimg, Vimg, o_bf);

            gemm_bf16_s<<<dim3(DMODEL / 128, C / 64), blk, 0, stream>>>(
                o_bf, wt_p, attn_proj_b + l * DMODEL, h_f, x_f, DMODEL, DMODEL);

            ln_v2<<<dim3(C / 4), blk, 0, stream>>>(
                x_f, ln2_g + l * DMODEL, ln2_b + l * DMODEL, h_f, h_bf);

            gemm_bf16<1, false, true><<<dim3(D4 / 128, C / 128), blk, 0, stream>>>(
                h_bf, wt_f, fc_b + l * D4, nullptr, mid_bf, D4, DMODEL);

            gemm_bf16_s<<<dim3(DMODEL / 128, C / 64), blk, 0, stream>>>(
                mid_bf, wt_m, mlp_proj_b + l * DMODEL, h_f, x_f, DMODEL, D4);
        }

        ln_v2<<<dim3(C / 4), blk, 0, stream>>>(x_f, lnf_g, lnf_b, nullptr, h_bf);

        gemm_logits<<<dim3(6400), blk, 0, stream>>>(h_bf, wt_out, out_b, out);
        return;
    }

    // ================= fallback f32 path =================
    const size_t n_x   = (size_t)C * DMODEL;
    const size_t n_qkv = (size_t)C * D3;
    const size_t need_bytes = (3 * n_x + n_qkv + (size_t)C * D4) * sizeof(float);

    float *x, *h, *o, *qkv, *mid;
    float* ws = (float*)d_ws;
    if (ws_size >= need_bytes) {
        x = ws; h = x + n_x; o = h + n_x; qkv = o + n_x; mid = qkv + n_qkv;
    } else {
        x = ws; h = x + n_x; o = h + n_x;
        qkv = (float*)d_out; mid = qkv + n_qkv;
    }

    embed_k<<<dim3(C), blk, 0, stream>>>(tokens, vocab_embed, pos_embed, x);
    for (int l = 0; l < LAYERS; l++) {
        const float* lw;
        layernorm_k<<<dim3(C), blk, 0, stream>>>(x, ln1_g + l * DMODEL, ln1_b + l * DMODEL, h);
        lw = att_w + (size_t)l * DMODEL * D3;
        gemm_f32<<<dim3(D3 / BN, C / BM), blk, 0, stream>>>(
            h, lw, att_b + l * D3, nullptr, qkv, C, D3, DMODEL, 0);
        attn_k<<<dim3(C, NHEAD), blk, 0, stream>>>(qkv, o);
        lw = attn_proj_w + (size_t)l * DMODEL * DMODEL;
        gemm_f32<<<dim3(DMODEL / BN, C / BM), blk, 0, stream>>>(
            o, lw, attn_proj_b + l * DMODEL, h, x, C, DMODEL, DMODEL, 0);
        layernorm_k<<<dim3(C), blk, 0, stream>>>(x, ln2_g + l * DMODEL, ln2_b + l * DMODEL, h);
        lw = fc_w + (size_t)l * DMODEL * D4;
        gemm_f32<<<dim3(D4 / BN, C / BM), blk, 0, stream>>>(
            h, lw, fc_b + l * D4, nullptr, mid, C, D4, DMODEL, 1);
        lw = mlp_proj_w + (size_t)l * D4 * DMODEL;
        gemm_f32<<<dim3(DMODEL / BN, C / BM), blk, 0, stream>>>(
            mid, lw, mlp_proj_b + l * DMODEL, h, x, C, DMODEL, D4, 0);
    }
    layernorm_k<<<dim3(C), blk, 0, stream>>>(x, lnf_g, lnf_b, h);
    gemm_f32<<<dim3((NVOCAB + BN - 1) / BN, C / BM), blk, 0, stream>>>(
        h, out_w, out_b, nullptr, out, C, NVOCAB, DMODEL, 0);
}